// Round 11
// baseline (171.779 us; speedup 1.0000x reference)
//
#include <hip/hip_runtime.h>
#include <hip/hip_bf16.h>
#include <stdint.h>

// B=4, T=2048, C=1024, H=16, hd=64
// qkv bf16 [8192][3072] (cols: 0..1023=Q, 1024..2047=K, 2048..3071=V; within: h*64+d)
//   NOTE: Wq/bq are pre-scaled by log2(e)/32, so S_qk = log2(e)*q.k/32 and softmax = exp2(S).
// vT bf16 [(bb*16+h)*64+d][2048]: vT[.][t*64+c'] = V[t*64+sigma(c')][d], sigma(c')=(c'&3)*16+(c'>>2)
// attn: causal flash, no-max softmax, exp2-based; 2 waves x 32 q-rows
// out:  O[8192,1024] @ Wp + bp -> fp32
// GEMMs: 256x256 tile, BK=64, 8 waves x (128x64 wave tile, acc[8][4]) -> 43.7 FLOP/LDS-byte,
// A/B dbuf + stage-ahead-1 (barrier-free interior), XOR swizzle, XCD swizzle, setprio.

typedef unsigned short u16;
typedef __attribute__((ext_vector_type(4))) float f32x4;
typedef __attribute__((ext_vector_type(8))) __bf16 bf16x8;
typedef __attribute__((ext_vector_type(2))) __bf16 bf16x2;

#define DEV static __device__ __forceinline__

DEV u16 f2bf(float f) {  // RNE float->bf16 (finite inputs only)
  uint32_t u = __builtin_bit_cast(uint32_t, f);
  return (u16)((u + 0x7FFFu + ((u >> 16) & 1u)) >> 16);
}

DEV uint pack2(float a, float b) {  // v_cvt_pk_bf16_f32 via vector of casts
  bf16x2 v;
  v.x = (__bf16)a;
  v.y = (__bf16)b;
  return __builtin_bit_cast(uint, v);
}

#if __has_builtin(__builtin_amdgcn_exp2f)
DEV float fexp2(float x) { return __builtin_amdgcn_exp2f(x); }
#else
DEV float fexp2(float x) { return __expf(x * 0.69314718056f); }
#endif

DEV void gload_lds16(const void* g, void* lds) {  // 16B/lane global->LDS direct
  auto gp = reinterpret_cast<const __attribute__((address_space(1))) uint32_t*>(
      reinterpret_cast<uintptr_t>(g));
  auto lp = reinterpret_cast<__attribute__((address_space(3))) uint32_t*>(
      static_cast<uint32_t>(reinterpret_cast<uintptr_t>(lds)));
  __builtin_amdgcn_global_load_lds(gp, lp, 16, 0, 0);
}

DEV f32x4 mfma16(bf16x8 a, bf16x8 b, f32x4 c) {
  return __builtin_amdgcn_mfma_f32_16x16x32_bf16(a, b, c, 0, 0, 0);
}

DEV void bar() {  // raw s_barrier + compiler memory fence
  asm volatile("" ::: "memory");
  __builtin_amdgcn_s_barrier();
  asm volatile("" ::: "memory");
}

#define LD8(p) (*reinterpret_cast<const bf16x8*>(p))
#define LDU4(p) (*reinterpret_cast<const uint4*>(p))

// ---------------- conversion kernels ----------------

__global__ void cvt_x_kernel(const float* __restrict__ x, u16* __restrict__ xb, int n8) {
  int i = blockIdx.x * blockDim.x + threadIdx.x;
  int stride = gridDim.x * blockDim.x;
  for (; i < n8; i += stride) {
    const float4* xp = reinterpret_cast<const float4*>(x) + 2 * (size_t)i;
    float4 a = xp[0], b = xp[1];
    uint4 o;
    o.x = pack2(a.x, a.y);
    o.y = pack2(a.z, a.w);
    o.z = pack2(b.x, b.y);
    o.w = pack2(b.z, b.w);
    reinterpret_cast<uint4*>(xb)[i] = o;
  }
}

// Wq/Wk/Wv [16][1024][64] -> wt[n=which*1024+h*64+d][c] (bf16), biasq[n].
__global__ void cvt_wqkv_kernel(const float* __restrict__ Wq, const float* __restrict__ Wk,
                                const float* __restrict__ Wv, const float* __restrict__ bq,
                                const float* __restrict__ bk, const float* __restrict__ bv,
                                u16* __restrict__ wt, float* __restrict__ biasq) {
  __shared__ u16 tle[64 * 72];
  const int tid = threadIdx.x;
  const int ct = blockIdx.x;     // c-tile 0..15
  const int h = blockIdx.y;      // 0..15
  const int which = blockIdx.z;  // 0..2
  const float* W = (which == 0) ? Wq : (which == 1) ? Wk : Wv;
  const float* Bb = (which == 0) ? bq : (which == 1) ? bk : bv;
  const float scl = (which == 0) ? 0.045084220027780106f : 1.0f;  // log2(e)/32
#pragma unroll
  for (int i = 0; i < 4; ++i) {
    int idx = i * 256 + tid;
    int c_l = idx >> 4, d4 = (idx & 15) * 4;
    float4 v = *reinterpret_cast<const float4*>(&W[((size_t)(h * 1024 + ct * 64 + c_l)) * 64 + d4]);
    tle[(d4 + 0) * 72 + c_l] = f2bf(v.x * scl);
    tle[(d4 + 1) * 72 + c_l] = f2bf(v.y * scl);
    tle[(d4 + 2) * 72 + c_l] = f2bf(v.z * scl);
    tle[(d4 + 3) * 72 + c_l] = f2bf(v.w * scl);
  }
  __syncthreads();
#pragma unroll
  for (int i = 0; i < 2; ++i) {
    int idx = i * 256 + tid;
    int d_o = idx >> 3, c8 = (idx & 7) * 8;
    uint4 v = LDU4(&tle[d_o * 72 + c8]);
    *reinterpret_cast<uint4*>(&wt[(size_t)(which * 1024 + h * 64 + d_o) * 1024 + ct * 64 + c8]) = v;
  }
  if (ct == 0 && tid < 64) biasq[which * 1024 + h * 64 + tid] = Bb[h * 64 + tid] * scl;
}

// Wp [1024][1024] -> wpt[n][c] = Wp[c][n]
__global__ void cvt_wp_kernel(const float* __restrict__ Wp, u16* __restrict__ wpt) {
  __shared__ u16 tle[64 * 72];
  const int tid = threadIdx.x;
  const int ct = blockIdx.x;
  const int nt = blockIdx.y;
#pragma unroll
  for (int i = 0; i < 4; ++i) {
    int idx = i * 256 + tid;
    int c_l = idx >> 4, n4 = (idx & 15) * 4;
    float4 v = *reinterpret_cast<const float4*>(&Wp[(size_t)(ct * 64 + c_l) * 1024 + nt * 64 + n4]);
    tle[(n4 + 0) * 72 + c_l] = f2bf(v.x);
    tle[(n4 + 1) * 72 + c_l] = f2bf(v.y);
    tle[(n4 + 2) * 72 + c_l] = f2bf(v.z);
    tle[(n4 + 3) * 72 + c_l] = f2bf(v.w);
  }
  __syncthreads();
#pragma unroll
  for (int i = 0; i < 2; ++i) {
    int idx = i * 256 + tid;
    int n_o = idx >> 3, c8 = (idx & 7) * 8;
    uint4 v = LDU4(&tle[n_o * 72 + c8]);
    *reinterpret_cast<uint4*>(&wpt[(size_t)(nt * 64 + n_o) * 1024 + ct * 64 + c8]) = v;
  }
}

// qkv V-part -> vT[(bb*16+h)*64+d][2048], sigma-permuted per 64-token tile.
__global__ __launch_bounds__(256)
void transpose_v_kernel(const u16* __restrict__ qkv, u16* __restrict__ vT) {
  __shared__ alignas(16) u16 tle[64 * 72];
  const int tid = threadIdx.x;
  const int tt = blockIdx.x;  // token tile 0..31
  const int h = blockIdx.y;   // 0..15
  const int bb = blockIdx.z;  // 0..3
  const size_t rbase = ((size_t)bb * 2048 + tt * 64) * 3072 + 2048 + h * 64;
#pragma unroll
  for (int i = 0; i < 2; ++i) {
    int idx = i * 256 + tid;  // 0..511
    int s = idx >> 3, c8 = (idx & 7) * 8;
    *reinterpret_cast<uint4*>(&tle[s * 72 + c8]) = LDU4(&qkv[rbase + (size_t)s * 3072 + c8]);
  }
  __syncthreads();
#pragma unroll
  for (int i = 0; i < 2; ++i) {
    int idx = i * 256 + tid;
    int d = idx >> 3, cb = idx & 7;
    uint4 o;
    o.x = (uint)tle[(2 * cb + 0) * 72 + d] | ((uint)tle[(16 + 2 * cb + 0) * 72 + d] << 16);
    o.y = (uint)tle[(32 + 2 * cb + 0) * 72 + d] | ((uint)tle[(48 + 2 * cb + 0) * 72 + d] << 16);
    o.z = (uint)tle[(2 * cb + 1) * 72 + d] | ((uint)tle[(16 + 2 * cb + 1) * 72 + d] << 16);
    o.w = (uint)tle[(32 + 2 * cb + 1) * 72 + d] | ((uint)tle[(48 + 2 * cb + 1) * 72 + d] << 16);
    *reinterpret_cast<uint4*>(
        &vT[((size_t)(bb * 16 + h) * 64 + d) * 2048 + tt * 64 + cb * 8]) = o;
  }
}

// ---------------- GEMM: C[m][n] = sum_k A[m][k]*Bt[n][k] + bias[n] ----------------
// 256x256 tile, BK=64, 8 waves (2M x 4N), wave tile 128x64 (acc[8][4]).
// LDS: A dbuf 2x32KB + B dbuf 2x32KB = 128 KB (1 block/CU). Stage-ahead-1 into the other
// buffer (its readers drained before the previous K-tile's end barrier -> no WAR);
// loads get a full K-tile (~2000 cyc) to land, so end-of-tile vmcnt(0) is cheap.
// Swizzle (r9-verified): LDS linear; global col-slot (tid&7)^(srow&7) on stage;
// read slot t -> t^(row&7). Zero bank conflicts.

template <bool OUT_F32>
__global__ __launch_bounds__(512, 2)
void gemm11_kernel(const u16* __restrict__ A, const u16* __restrict__ Bt,
                   const float* __restrict__ bias, void* __restrict__ Cout,
                   int M, int N, int K, int nbn) {
  __shared__ alignas(16) u16 LA[2 * 16384];  // 2 x (256x64) = 64 KB
  __shared__ alignas(16) u16 LB[2 * 16384];  // 64 KB

  const int tid = threadIdx.x;
  const int lane = tid & 63;
  const int wave = tid >> 6;   // 0..7
  const int wm = wave >> 2;    // 0..1  -> rows wm*128 .. +128
  const int wn = wave & 3;     // 0..3  -> cols wn*64 .. +64
  const int fr = lane & 15;
  const int kg = lane >> 4;    // 0..3
  const int f7 = fr & 7;
  const int r4 = kg * 4;

  const int nwg = gridDim.x;  // multiple of 8
  const int swz = (blockIdx.x & 7) * (nwg >> 3) + (blockIdx.x >> 3);
  const int m0 = (swz / nbn) * 256;
  const int n0 = (swz % nbn) * 256;

  const int NT = K >> 6;

  const int srow = tid >> 3;                        // 0..63 (row within 64-row quad)
  const int sgcol = ((tid & 7) ^ (srow & 7)) << 3;  // inverse-swizzled global col slot (u16)
  const size_t aOff = (size_t)(m0 + srow) * K + sgcol;
  const size_t bOff = (size_t)(n0 + srow) * K + sgcol;
  const int ldst = tid * 8;  // u16: linear LDS chunk within an 8 KB quad-stage

  auto stageA = [&](int kt, u16* d) {  // 4 quads = 256 rows
    gload_lds16(A + aOff + (size_t)kt * 64, d + ldst);
    gload_lds16(A + aOff + (size_t)64 * K + (size_t)kt * 64, d + 4096 + ldst);
    gload_lds16(A + aOff + (size_t)128 * K + (size_t)kt * 64, d + 8192 + ldst);
    gload_lds16(A + aOff + (size_t)192 * K + (size_t)kt * 64, d + 12288 + ldst);
  };
  auto stageB = [&](int kt, u16* d) {
    gload_lds16(Bt + bOff + (size_t)kt * 64, d + ldst);
    gload_lds16(Bt + bOff + (size_t)64 * K + (size_t)kt * 64, d + 4096 + ldst);
    gload_lds16(Bt + bOff + (size_t)128 * K + (size_t)kt * 64, d + 8192 + ldst);
    gload_lds16(Bt + bOff + (size_t)192 * K + (size_t)kt * 64, d + 12288 + ldst);
  };

  f32x4 acc[8][4] = {};

  // prologue
  stageA(0, LA);
  stageB(0, LB);
  asm volatile("s_waitcnt vmcnt(0)" ::: "memory");
  bar();

  for (int kt = 0; kt < NT; ++kt) {
    const bool st1 = (kt + 1 < NT);
    u16* la = LA + (kt & 1) * 16384;
    u16* lb = LB + (kt & 1) * 16384;

    if (st1) {
      stageA(kt + 1, LA + ((kt + 1) & 1) * 16384);
      stageB(kt + 1, LB + ((kt + 1) & 1) * 16384);
    }

#pragma unroll
    for (int ks = 0; ks < 2; ++ks) {
      const int ko = ((ks * 4 + kg) ^ f7) << 3;
      bf16x8 bfr[4];
#pragma unroll
      for (int n = 0; n < 4; ++n)
        bfr[n] = LD8(&lb[(wn * 64 + n * 16 + fr) * 64 + ko]);
      __builtin_amdgcn_s_setprio(1);
#pragma unroll
      for (int m = 0; m < 8; ++m) {
        bf16x8 a = LD8(&la[(wm * 128 + m * 16 + fr) * 64 + ko]);
#pragma unroll
        for (int n = 0; n < 4; ++n)
          acc[m][n] = mfma16(a, bfr[n], acc[m][n]);
      }
      __builtin_amdgcn_s_setprio(0);
    }

    if (st1) {
      asm volatile("s_waitcnt vmcnt(0)" ::: "memory");
      bar();
    }
  }

  // epilogue
#pragma unroll
  for (int m = 0; m < 8; ++m) {
    const int row = m0 + wm * 128 + m * 16 + r4;
#pragma unroll
    for (int n = 0; n < 4; ++n) {
      const int col = n0 + wn * 64 + n * 16 + fr;
      const float bv = bias[col];
#pragma unroll
      for (int r = 0; r < 4; ++r) {
        float v = acc[m][n][r] + bv;
        size_t off = (size_t)(row + r) * N + col;
        if constexpr (OUT_F32) reinterpret_cast<float*>(Cout)[off] = v;
        else                   reinterpret_cast<u16*>(Cout)[off] = f2bf(v);
      }
    }
  }
}

// ---------------- causal flash attention: 2 waves x 32 q-rows (unchanged, r10) ----------------

__global__ __launch_bounds__(128, 2)
void attn_kernel(const u16* __restrict__ qkv, const u16* __restrict__ vT,
                 u16* __restrict__ obuf) {
  __shared__ alignas(16) u16 Ks[64 * 72];
  __shared__ alignas(16) u16 Vs[64 * 72];
  __shared__ alignas(16) u16 Ps[2][32 * 72];

  const int tid = threadIdx.x;
  const int lane = tid & 63;
  const int wave = tid >> 6;  // 0..1

  const int gid = blockIdx.x;
  const int xcd = gid & 7;
  const int jj = gid >> 3;
  const int g = xcd * 8 + (jj >> 4);
  const int pair = jj & 15;
  const int bb = g >> 4;
  const int h = g & 15;

  const size_t baseQ = (size_t)bb * 2048 * 3072 + h * 64;
  const size_t baseK = baseQ + 1024;
  const size_t baseVt = (size_t)(bb * 16 + h) * 64 * 2048;

  const int fr = lane & 15;
  const int kg8 = (lane >> 4) * 8;
  const int qw32 = wave * 32;
  const int r4 = (lane >> 4) * 4;

  const int rrA = tid >> 3;       // 0..15
  const int cA8 = (tid & 7) * 8;
  const size_t gK = (size_t)rrA * 3072 + cA8;
  const size_t gV = (size_t)rrA * 2048 + cA8;
  const int lof = rrA * 72 + cA8;
  u16* __restrict__ Pw = &Ps[wave][0];

  for (int half = 0; half < 2; ++half) {
    const int qt = half ? (31 - pair) : pair;
    const int q0 = qt * 64;
    const int nt = qt + 1;

    const u16* qrow0 = &qkv[baseQ + (size_t)(q0 + qw32 + fr) * 3072 + kg8];
    bf16x8 aq00 = LD8(qrow0), aq01 = LD8(qrow0 + 32);
    const u16* qrow1 = qrow0 + 16 * 3072;
    bf16x8 aq10 = LD8(qrow1), aq11 = LD8(qrow1 + 32);

    float lsA0 = 0.f, lsA1 = 0.f, lsA2 = 0.f, lsA3 = 0.f;
    float lsB0 = 0.f, lsB1 = 0.f, lsB2 = 0.f, lsB3 = 0.f;
    f32x4 oA0 = {}, oA1 = {}, oA2 = {}, oA3 = {};
    f32x4 oB0 = {}, oB1 = {}, oB2 = {}, oB3 = {};

    uint4 kr0 = LDU4(&qkv[baseK + gK]);
    uint4 kr1 = LDU4(&qkv[baseK + gK + 49152]);
    uint4 kr2 = LDU4(&qkv[baseK + gK + 98304]);
    uint4 kr3 = LDU4(&qkv[baseK + gK + 147456]);
    uint4 vr0 = LDU4(&vT[baseVt + gV]);
    uint4 vr1 = LDU4(&vT[baseVt + gV + 32768]);
    uint4 vr2 = LDU4(&vT[baseVt + gV + 65536]);
    uint4 vr3 = LDU4(&vT[baseVt + gV + 98304]);

    for (int t = 0; t < nt; ++t) {
      __syncthreads();
      *reinterpret_cast<uint4*>(&Ks[lof]) = kr0;
      *reinterpret_cast<uint4*>(&Ks[lof + 1152]) = kr1;
      *reinterpret_cast<uint4*>(&Ks[lof + 2304]) = kr2;
      *reinterpret_cast<uint4*>(&Ks[lof + 3456]) = kr3;
      *reinterpret_cast<uint4*>(&Vs[lof]) = vr0;
      *reinterpret_cast<uint4*>(&Vs[lof + 1152]) = vr1;
      *reinterpret_cast<uint4*>(&Vs[lof + 2304]) = vr2;
      *reinterpret_cast<uint4*>(&Vs[lof + 3456]) = vr3;
      if (t + 1 < nt) {
        const u16* nk = &qkv[baseK + (size_t)(t + 1) * 196608];
        const u16* nv = &vT[baseVt + (size_t)(t + 1) * 64];
        kr0 = LDU4(nk + gK);
        kr1 = LDU4(nk + gK + 49152);
        kr2 = LDU4(nk + gK + 98304);
        kr3 = LDU4(nk + gK + 147456);
        vr0 = LDU4(nv + gV);
        vr1 = LDU4(nv + gV + 32768);
        vr2 = LDU4(nv + gV + 65536);
        vr3 = LDU4(nv + gV + 98304);
      }
      __syncthreads();

      f32x4 sA0 = {}, sA1 = {}, sA2 = {}, sA3 = {};
      f32x4 sB0 = {}, sB1 = {}, sB2 = {}, sB3 = {};
      {
        bf16x8 b;
        __builtin_amdgcn_s_setprio(1);
        b = LD8(&Ks[(fr) * 72 + kg8]);           sA0 = mfma16(aq00, b, sA0); sB0 = mfma16(aq10, b, sB0);
        b = LD8(&Ks[(16 + fr) * 72 + kg8]);      sA1 = mfma16(aq00, b, sA1); sB1 = mfma16(aq10, b, sB1);
        b = LD8(&Ks[(32 + fr) * 72 + kg8]);      sA2 = mfma16(aq00, b, sA2); sB2 = mfma16(aq10, b, sB2);
        b = LD8(&Ks[(48 + fr) * 72 + kg8]);      sA3 = mfma16(aq00, b, sA3); sB3 = mfma16(aq10, b, sB3);
        b = LD8(&Ks[(fr) * 72 + 32 + kg8]);      sA0 = mfma16(aq01, b, sA0); sB0 = mfma16(aq11, b, sB0);
        b = LD8(&Ks[(16 + fr) * 72 + 32 + kg8]); sA1 = mfma16(aq01, b, sA1); sB1 = mfma16(aq11, b, sB1);
        b = LD8(&Ks[(32 + fr) * 72 + 32 + kg8]); sA2 = mfma16(aq01, b, sA2); sB2 = mfma16(aq11, b, sB2);
        b = LD8(&Ks[(48 + fr) * 72 + 32 + kg8]); sA3 = mfma16(aq01, b, sA3); sB3 = mfma16(aq11, b, sB3);
        __builtin_amdgcn_s_setprio(0);
      }

      const bool diag = (t == nt - 1);
#define SM_ROW_G(S0, S1, S2, S3, LS, RB, r)                                    \
      {                                                                        \
        const int qg = qw32 + RB + r4 + r;                                     \
        float p0 = fexp2(S0[r]);                                               \
        float p1 = fexp2(S1[r]);                                               \
        float p2 = fexp2(S2[r]);                                               \
        float p3 = fexp2(S3[r]);                                               \
        if (diag) {                                                            \
          if (fr > qg) p0 = 0.f;                                               \
          if (fr + 16 > qg) p1 = 0.f;                                          \
          if (fr + 32 > qg) p2 = 0.f;                                          \
          if (fr + 48 > qg) p3 = 0.f;                                          \
        }                                                                      \
        LS += (p0 + p1) + (p2 + p3);                                           \
        uint2 w;                                                               \
        w.x = pack2(p0, p1);                                                   \
        w.y = pack2(p2, p3);                                                   \
        *reinterpret_cast<uint2*>(&Pw[(RB + r4 + r) * 72 + fr * 4]) = w;       \
      }
      SM_ROW_G(sA0, sA1, sA2, sA3, lsA0, 0, 0)
      SM_ROW_G(sA0, sA1, sA2, sA3, lsA1, 0, 1)
      SM_ROW_G(sA0, sA1, sA2, sA3, lsA2, 0, 2)
      SM_ROW_G(sA0, sA1, sA2, sA3, lsA3, 0, 3)
      SM_ROW_G(sB0, sB1, sB2, sB3, lsB0, 16, 0)
      SM_ROW_G(sB0, sB1, sB2, sB3, lsB1, 16, 1)
      SM_ROW_G(sB0, sB1, sB2, sB3, lsB2, 16, 2)
      SM_ROW_G(sB0, sB1, sB2, sB3, lsB3, 16, 3)
#undef SM_ROW_G

      {
        bf16x8 pfA = LD8(&Pw[fr * 72 + kg8]);
        bf16x8 pfB = LD8(&Pw[(16 + fr) * 72 + kg8]);
        bf16x8 v;
        __builtin_amdgcn_s_setprio(1);
        v = LD8(&Vs[(fr) * 72 + kg8]);           oA0 = mfma16(pfA, v, oA0); oB0 = mfma16(pfB, v, oB0);
        v = LD8(&Vs[(16 + fr) * 72 + kg8]);      oA1 = mfma16(pfA, v, oA1); oB1 = mfma16(pfB, v, oB1);
        v = LD8(&Vs[(32 + fr) * 72 + kg8]);      oA2 = mfma16(pfA, v, oA2); oB2 = mfma16(pfB, v, oB2);
        v = LD8(&Vs[(48 + fr) * 72 + kg8]);      oA3 = mfma16(pfA, v, oA3); oB3 = mfma16(pfB, v, oB3);
        pfA = LD8(&Pw[fr * 72 + 32 + kg8]);
        pfB = LD8(&Pw[(16 + fr) * 72 + 32 + kg8]);
        v = LD8(&Vs[(fr) * 72 + 32 + kg8]);      oA0 = mfma16(pfA, v, oA0); oB0 = mfma16(pfB, v, oB0);
        v = LD8(&Vs[(16 + fr) * 72 + 32 + kg8]); oA1 = mfma16(pfA, v, oA1); oB1 = mfma16(pfB, v, oB1);
        v = LD8(&Vs[(32 + fr) * 72 + 32 + kg8]); oA2 = mfma16(pfA, v, oA2); oB2 = mfma16(pfB, v, oB2);
        v = LD8(&Vs[(48 + fr) * 72 + 32 + kg8]); oA3 = mfma16(pfA, v, oA3); oB3 = mfma16(pfB, v, oB3);
        __builtin_amdgcn_s_setprio(0);
      }
    }

#define EPI_G(O0, O1, O2, O3, LS, RB, r)                                       \
    {                                                                          \
      float s = LS;                                                            \
      s += __shfl_xor(s, 1);                                                   \
      s += __shfl_xor(s, 2);                                                   \
      s += __shfl_xor(s, 4);                                                   \
      s += __shfl_xor(s, 8);                                                   \
      const float inv = 1.0f / s;                                              \
      const int qg = q0 + qw32 + RB + r4 + r;                                  \
      const size_t rowoff = ((size_t)bb * 2048 + qg) * 1024 + h * 64;          \
      obuf[rowoff + fr] = f2bf(O0[r] * inv);                                   \
      obuf[rowoff + 16 + fr] = f2bf(O1[r] * inv);                              \
      obuf[rowoff + 32 + fr] = f2bf(O2[r] * inv);                              \
      obuf[rowoff + 48 + fr] = f2bf(O3[r] * inv);                              \
    }
    EPI_G(oA0, oA1, oA2, oA3, lsA0, 0, 0)
    EPI_G(oA0, oA1, oA2, oA3, lsA1, 0, 1)
    EPI_G(oA0, oA1, oA2, oA3, lsA2, 0, 2)
    EPI_G(oA0, oA1, oA2, oA3, lsA3, 0, 3)
    EPI_G(oB0, oB1, oB2, oB3, lsB0, 16, 0)
    EPI_G(oB0, oB1, oB2, oB3, lsB1, 16, 1)
    EPI_G(oB0, oB1, oB2, oB3, lsB2, 16, 2)
    EPI_G(oB0, oB1, oB2, oB3, lsB3, 16, 3)
#undef EPI_G
  }
}

// ---------------- launch ----------------

extern "C" void kernel_launch(void* const* d_in, const int* in_sizes, int n_in,
                              void* d_out, int out_size, void* d_ws, size_t ws_size,
                              hipStream_t stream) {
  const float* x  = (const float*)d_in[0];
  const float* Wq = (const float*)d_in[1];
  const float* bq = (const float*)d_in[2];
  const float* Wk = (const float*)d_in[3];
  const float* bk = (const float*)d_in[4];
  const float* Wv = (const float*)d_in[5];
  const float* bv = (const float*)d_in[6];
  const float* Wp = (const float*)d_in[7];
  const float* bp = (const float*)d_in[8];

  char* ws = (char*)d_ws;
  size_t off = 0;
  auto alloc = [&](size_t bytes) -> void* {
    void* p = ws + off;
    off += (bytes + 255) & ~(size_t)255;
    return p;
  };
  u16*   xb     = (u16*)  alloc((size_t)8192 * 1024 * 2);  // reused as vT after QKV GEMM
  u16*   wqkv_t = (u16*)  alloc((size_t)3072 * 1024 * 2);
  float* biasq  = (float*)alloc((size_t)3072 * 4);
  u16*   wpt    = (u16*)  alloc((size_t)1024 * 1024 * 2);
  u16*   qkv    = (u16*)  alloc((size_t)8192 * 3072 * 2);
  u16*   obuf   = (u16*)  alloc((size_t)8192 * 1024 * 2);
  u16*   vT     = xb;  // xb is dead after the QKV GEMM; vT is exactly 16 MB too
  (void)ws_size; (void)in_sizes; (void)n_in; (void)out_size;

  cvt_x_kernel<<<2048, 256, 0, stream>>>(x, xb, 8192 * 1024 / 8);
  cvt_wqkv_kernel<<<dim3(16, 16, 3), 256, 0, stream>>>(Wq, Wk, Wv, bq, bk, bv, wqkv_t, biasq);
  cvt_wp_kernel<<<dim3(16, 16), 256, 0, stream>>>(Wp, wpt);
  gemm11_kernel<false><<<384, 512, 0, stream>>>(xb, wqkv_t, biasq, qkv, 8192, 3072, 1024, 12);
  transpose_v_kernel<<<dim3(32, 16, 4), 256, 0, stream>>>(qkv, vT);
  attn_kernel<<<1024, 128, 0, stream>>>(qkv, vT, obuf);
  gemm11_kernel<true><<<128, 512, 0, stream>>>(obuf, wpt, bp, d_out, 8192, 1024, 1024, 4);
}

// Round 12
// 163.944 us; speedup vs baseline: 1.0478x; 1.0478x over previous
//
#include <hip/hip_runtime.h>
#include <hip/hip_bf16.h>
#include <stdint.h>

// B=4, T=2048, C=1024, H=16, hd=64
// qkv bf16 [8192][3072] (cols: 0..1023=Q, 1024..2047=K, 2048..3071=V; within: h*64+d)
//   NOTE: Wq/bq are pre-scaled by log2(e)/32, so softmax = exp2(S).
// vT bf16 [(bb*16+h)*64+d][2048]: sigma-permuted per 64-token tile.
// QKV GEMM: gemm12 = 256x256, BK=64, 4-phase/K-tile interleave (T3+T4+T5), dbuf LDS,
//   derived WAR-free staging rhythm, one counted vmcnt(2) per K-tile, XOR swizzle.
// proj GEMM: gemm9 (128x256, verified, 256 blocks = exactly 1 round).

typedef unsigned short u16;
typedef __attribute__((ext_vector_type(4))) float f32x4;
typedef __attribute__((ext_vector_type(8))) __bf16 bf16x8;
typedef __attribute__((ext_vector_type(2))) __bf16 bf16x2;

#define DEV static __device__ __forceinline__

DEV u16 f2bf(float f) {  // RNE float->bf16 (finite inputs only)
  uint32_t u = __builtin_bit_cast(uint32_t, f);
  return (u16)((u + 0x7FFFu + ((u >> 16) & 1u)) >> 16);
}

DEV uint pack2(float a, float b) {  // v_cvt_pk_bf16_f32 via vector of casts
  bf16x2 v;
  v.x = (__bf16)a;
  v.y = (__bf16)b;
  return __builtin_bit_cast(uint, v);
}

#if __has_builtin(__builtin_amdgcn_exp2f)
DEV float fexp2(float x) { return __builtin_amdgcn_exp2f(x); }
#else
DEV float fexp2(float x) { return __expf(x * 0.69314718056f); }
#endif

DEV void gload_lds16(const void* g, void* lds) {  // 16B/lane global->LDS direct
  auto gp = reinterpret_cast<const __attribute__((address_space(1))) uint32_t*>(
      reinterpret_cast<uintptr_t>(g));
  auto lp = reinterpret_cast<__attribute__((address_space(3))) uint32_t*>(
      static_cast<uint32_t>(reinterpret_cast<uintptr_t>(lds)));
  __builtin_amdgcn_global_load_lds(gp, lp, 16, 0, 0);
}

DEV f32x4 mfma16(bf16x8 a, bf16x8 b, f32x4 c) {
  return __builtin_amdgcn_mfma_f32_16x16x32_bf16(a, b, c, 0, 0, 0);
}

DEV void bar() {  // raw s_barrier + compiler memory fence
  asm volatile("" ::: "memory");
  __builtin_amdgcn_s_barrier();
  asm volatile("" ::: "memory");
}

#define LD8(p) (*reinterpret_cast<const bf16x8*>(p))
#define LDU4(p) (*reinterpret_cast<const uint4*>(p))

// ---------------- conversion kernels ----------------

__global__ void cvt_x_kernel(const float* __restrict__ x, u16* __restrict__ xb, int n8) {
  int i = blockIdx.x * blockDim.x + threadIdx.x;
  int stride = gridDim.x * blockDim.x;
  for (; i < n8; i += stride) {
    const float4* xp = reinterpret_cast<const float4*>(x) + 2 * (size_t)i;
    float4 a = xp[0], b = xp[1];
    uint4 o;
    o.x = pack2(a.x, a.y);
    o.y = pack2(a.z, a.w);
    o.z = pack2(b.x, b.y);
    o.w = pack2(b.z, b.w);
    reinterpret_cast<uint4*>(xb)[i] = o;
  }
}

// Wq/Wk/Wv [16][1024][64] -> wt[n=which*1024+h*64+d][c] (bf16), biasq[n].
__global__ void cvt_wqkv_kernel(const float* __restrict__ Wq, const float* __restrict__ Wk,
                                const float* __restrict__ Wv, const float* __restrict__ bq,
                                const float* __restrict__ bk, const float* __restrict__ bv,
                                u16* __restrict__ wt, float* __restrict__ biasq) {
  __shared__ u16 tle[64 * 72];
  const int tid = threadIdx.x;
  const int ct = blockIdx.x;     // c-tile 0..15
  const int h = blockIdx.y;      // 0..15
  const int which = blockIdx.z;  // 0..2
  const float* W = (which == 0) ? Wq : (which == 1) ? Wk : Wv;
  const float* Bb = (which == 0) ? bq : (which == 1) ? bk : bv;
  const float scl = (which == 0) ? 0.045084220027780106f : 1.0f;  // log2(e)/32
#pragma unroll
  for (int i = 0; i < 4; ++i) {
    int idx = i * 256 + tid;
    int c_l = idx >> 4, d4 = (idx & 15) * 4;
    float4 v = *reinterpret_cast<const float4*>(&W[((size_t)(h * 1024 + ct * 64 + c_l)) * 64 + d4]);
    tle[(d4 + 0) * 72 + c_l] = f2bf(v.x * scl);
    tle[(d4 + 1) * 72 + c_l] = f2bf(v.y * scl);
    tle[(d4 + 2) * 72 + c_l] = f2bf(v.z * scl);
    tle[(d4 + 3) * 72 + c_l] = f2bf(v.w * scl);
  }
  __syncthreads();
#pragma unroll
  for (int i = 0; i < 2; ++i) {
    int idx = i * 256 + tid;
    int d_o = idx >> 3, c8 = (idx & 7) * 8;
    uint4 v = LDU4(&tle[d_o * 72 + c8]);
    *reinterpret_cast<uint4*>(&wt[(size_t)(which * 1024 + h * 64 + d_o) * 1024 + ct * 64 + c8]) = v;
  }
  if (ct == 0 && tid < 64) biasq[which * 1024 + h * 64 + tid] = Bb[h * 64 + tid] * scl;
}

// Wp [1024][1024] -> wpt[n][c] = Wp[c][n]
__global__ void cvt_wp_kernel(const float* __restrict__ Wp, u16* __restrict__ wpt) {
  __shared__ u16 tle[64 * 72];
  const int tid = threadIdx.x;
  const int ct = blockIdx.x;
  const int nt = blockIdx.y;
#pragma unroll
  for (int i = 0; i < 4; ++i) {
    int idx = i * 256 + tid;
    int c_l = idx >> 4, n4 = (idx & 15) * 4;
    float4 v = *reinterpret_cast<const float4*>(&Wp[(size_t)(ct * 64 + c_l) * 1024 + nt * 64 + n4]);
    tle[(n4 + 0) * 72 + c_l] = f2bf(v.x);
    tle[(n4 + 1) * 72 + c_l] = f2bf(v.y);
    tle[(n4 + 2) * 72 + c_l] = f2bf(v.z);
    tle[(n4 + 3) * 72 + c_l] = f2bf(v.w);
  }
  __syncthreads();
#pragma unroll
  for (int i = 0; i < 2; ++i) {
    int idx = i * 256 + tid;
    int n_o = idx >> 3, c8 = (idx & 7) * 8;
    uint4 v = LDU4(&tle[n_o * 72 + c8]);
    *reinterpret_cast<uint4*>(&wpt[(size_t)(nt * 64 + n_o) * 1024 + ct * 64 + c8]) = v;
  }
}

// qkv V-part -> vT[(bb*16+h)*64+d][2048], sigma-permuted per 64-token tile.
__global__ __launch_bounds__(256)
void transpose_v_kernel(const u16* __restrict__ qkv, u16* __restrict__ vT) {
  __shared__ alignas(16) u16 tle[64 * 72];
  const int tid = threadIdx.x;
  const int tt = blockIdx.x;  // token tile 0..31
  const int h = blockIdx.y;   // 0..15
  const int bb = blockIdx.z;  // 0..3
  const size_t rbase = ((size_t)bb * 2048 + tt * 64) * 3072 + 2048 + h * 64;
#pragma unroll
  for (int i = 0; i < 2; ++i) {
    int idx = i * 256 + tid;  // 0..511
    int s = idx >> 3, c8 = (idx & 7) * 8;
    *reinterpret_cast<uint4*>(&tle[s * 72 + c8]) = LDU4(&qkv[rbase + (size_t)s * 3072 + c8]);
  }
  __syncthreads();
#pragma unroll
  for (int i = 0; i < 2; ++i) {
    int idx = i * 256 + tid;
    int d = idx >> 3, cb = idx & 7;
    uint4 o;
    o.x = (uint)tle[(2 * cb + 0) * 72 + d] | ((uint)tle[(16 + 2 * cb + 0) * 72 + d] << 16);
    o.y = (uint)tle[(32 + 2 * cb + 0) * 72 + d] | ((uint)tle[(48 + 2 * cb + 0) * 72 + d] << 16);
    o.z = (uint)tle[(2 * cb + 1) * 72 + d] | ((uint)tle[(16 + 2 * cb + 1) * 72 + d] << 16);
    o.w = (uint)tle[(32 + 2 * cb + 1) * 72 + d] | ((uint)tle[(48 + 2 * cb + 1) * 72 + d] << 16);
    *reinterpret_cast<uint4*>(
        &vT[((size_t)(bb * 16 + h) * 64 + d) * 2048 + tt * 64 + cb * 8]) = o;
  }
}

// ---------------- gemm12: 256x256, BK=64, 4-phase interleaved pipeline ----------------
// 8 waves (2M x 4N), wave tile 128x64, acc[8][4]. LDS: A dbuf 2x32KB + B dbuf 2x32KB.
// Phases p0=(ks0,mh0) p1=(ks0,mh1) p2=(ks1,mh0) p3=(ks1,mh1); B-frags read once per ks,
// held across mh phases. Staging rhythm (each target's last reader drained at a prior
// phase-end barrier): p0: A(kt+1)q{1,3}->bufN; p1: B(kt+1)q{0,1}->bufN; p2: B(kt+1)q{2,3};
// p3: A(kt+2)q{0,2}->CURRENT buf (its quads 0,2 last read in p2). One vmcnt(2) at p3
// (queue: [A(kt+1)q02, A(kt+1)q13, Bq01, Bq23, A(kt+2)q02] = 10; oldest 8 = all of kt+1).

template <bool OUT_F32>
__global__ __launch_bounds__(512, 2)
void gemm12_kernel(const u16* __restrict__ A, const u16* __restrict__ Bt,
                   const float* __restrict__ bias, void* __restrict__ Cout,
                   int M, int N, int K, int nbn) {
  __shared__ alignas(16) u16 LA[2 * 16384];  // 2 x (256x64) = 64 KB
  __shared__ alignas(16) u16 LB[2 * 16384];  // 64 KB

  const int tid = threadIdx.x;
  const int lane = tid & 63;
  const int wave = tid >> 6;   // 0..7
  const int wm = wave >> 2;    // 0..1
  const int wn = wave & 3;     // 0..3
  const int fr = lane & 15;
  const int kg = lane >> 4;    // 0..3
  const int f7 = fr & 7;
  const int r4 = kg * 4;

  const int nwg = gridDim.x;  // multiple of 8
  const int swz = (blockIdx.x & 7) * (nwg >> 3) + (blockIdx.x >> 3);
  const int m0 = (swz / nbn) * 256;
  const int n0 = (swz % nbn) * 256;
  const int NT = K >> 6;

  const int srow = tid >> 3;                        // 0..63 (row within quad)
  const int sgcol = ((tid & 7) ^ (srow & 7)) << 3;  // inverse-swizzled global col slot
  const size_t aOff = (size_t)(m0 + srow) * K + sgcol;
  const size_t bOff = (size_t)(n0 + srow) * K + sgcol;
  const int ldst = tid * 8;  // u16 within a quad

  auto stA = [&](int kt, int q, u16* d) {  // one 64-row quad, 8 KB, 1 gload
    gload_lds16(A + aOff + (size_t)(q * 64) * K + (size_t)kt * 64, d + q * 4096 + ldst);
  };
  auto stB = [&](int kt, int q, u16* d) {
    gload_lds16(Bt + bOff + (size_t)(q * 64) * K + (size_t)kt * 64, d + q * 4096 + ldst);
  };

  f32x4 acc[8][4] = {};

  // prologue: A(0),B(0) full -> buf0; A(1)q{0,2} -> buf1 (matches steady-state queue)
  stA(0, 0, LA); stA(0, 1, LA); stA(0, 2, LA); stA(0, 3, LA);
  stB(0, 0, LB); stB(0, 1, LB); stB(0, 2, LB); stB(0, 3, LB);
  if (NT > 1) {
    stA(1, 0, LA + 16384); stA(1, 2, LA + 16384);
    asm volatile("s_waitcnt vmcnt(2)" ::: "memory");
  } else {
    asm volatile("s_waitcnt vmcnt(0)" ::: "memory");
  }
  bar();

  for (int kt = 0; kt < NT; ++kt) {
    u16* la = LA + (kt & 1) * 16384;
    u16* lb = LB + (kt & 1) * 16384;
    u16* laN = LA + ((kt + 1) & 1) * 16384;
    u16* lbN = LB + ((kt + 1) & 1) * 16384;
    const int ko0 = (kg ^ f7) << 3;        // ks=0 swizzled slot
    const int ko1 = ((4 + kg) ^ f7) << 3;  // ks=1
    const bool st1 = (kt + 1 < NT);
    const bool st2 = (kt + 2 < NT);
    bf16x8 afr[4], bfr[4];

    // ---- p0: (ks0, mh0)
#pragma unroll
    for (int m = 0; m < 4; ++m) afr[m] = LD8(&la[(wm * 128 + m * 16 + fr) * 64 + ko0]);
#pragma unroll
    for (int n = 0; n < 4; ++n) bfr[n] = LD8(&lb[(wn * 64 + n * 16 + fr) * 64 + ko0]);
    if (st1) { stA(kt + 1, 1, laN); stA(kt + 1, 3, laN); }
    bar();
    __builtin_amdgcn_s_setprio(1);
#pragma unroll
    for (int m = 0; m < 4; ++m)
#pragma unroll
      for (int n = 0; n < 4; ++n) acc[m][n] = mfma16(afr[m], bfr[n], acc[m][n]);
    __builtin_amdgcn_s_setprio(0);
    bar();

    // ---- p1: (ks0, mh1) — reuse bfr
#pragma unroll
    for (int m = 0; m < 4; ++m) afr[m] = LD8(&la[(wm * 128 + (m + 4) * 16 + fr) * 64 + ko0]);
    if (st1) { stB(kt + 1, 0, lbN); stB(kt + 1, 1, lbN); }
    bar();
    __builtin_amdgcn_s_setprio(1);
#pragma unroll
    for (int m = 0; m < 4; ++m)
#pragma unroll
      for (int n = 0; n < 4; ++n) acc[m + 4][n] = mfma16(afr[m], bfr[n], acc[m + 4][n]);
    __builtin_amdgcn_s_setprio(0);
    bar();

    // ---- p2: (ks1, mh0)
#pragma unroll
    for (int m = 0; m < 4; ++m) afr[m] = LD8(&la[(wm * 128 + m * 16 + fr) * 64 + ko1]);
#pragma unroll
    for (int n = 0; n < 4; ++n) bfr[n] = LD8(&lb[(wn * 64 + n * 16 + fr) * 64 + ko1]);
    if (st1) { stB(kt + 1, 2, lbN); stB(kt + 1, 3, lbN); }
    bar();
    __builtin_amdgcn_s_setprio(1);
#pragma unroll
    for (int m = 0; m < 4; ++m)
#pragma unroll
      for (int n = 0; n < 4; ++n) acc[m][n] = mfma16(afr[m], bfr[n], acc[m][n]);
    __builtin_amdgcn_s_setprio(0);
    bar();

    // ---- p3: (ks1, mh1) — stage A(kt+2)q{0,2} into CURRENT buf (quads 0,2 drained at p2)
#pragma unroll
    for (int m = 0; m < 4; ++m) afr[m] = LD8(&la[(wm * 128 + (m + 4) * 16 + fr) * 64 + ko1]);
    if (st2) { stA(kt + 2, 0, la); stA(kt + 2, 2, la); }
    if (st1) {
      if (st2) asm volatile("s_waitcnt vmcnt(2)" ::: "memory");
      else     asm volatile("s_waitcnt vmcnt(0)" ::: "memory");
    }
    bar();
    __builtin_amdgcn_s_setprio(1);
#pragma unroll
    for (int m = 0; m < 4; ++m)
#pragma unroll
      for (int n = 0; n < 4; ++n) acc[m + 4][n] = mfma16(afr[m], bfr[n], acc[m + 4][n]);
    __builtin_amdgcn_s_setprio(0);
    bar();
  }

  // epilogue
#pragma unroll
  for (int m = 0; m < 8; ++m) {
    const int row = m0 + wm * 128 + m * 16 + r4;
#pragma unroll
    for (int n = 0; n < 4; ++n) {
      const int col = n0 + wn * 64 + n * 16 + fr;
      const float bv = bias[col];
#pragma unroll
      for (int r = 0; r < 4; ++r) {
        float v = acc[m][n][r] + bv;
        size_t off = (size_t)(row + r) * N + col;
        if constexpr (OUT_F32) reinterpret_cast<float*>(Cout)[off] = v;
        else                   reinterpret_cast<u16*>(Cout)[off] = f2bf(v);
      }
    }
  }
}

// ---------------- gemm9 (r9/r10-verified): 128x256, A-dbuf + B-tribuf, for proj ----------------

template <bool OUT_F32>
__global__ __launch_bounds__(512, 2)
void gemm9_kernel(const u16* __restrict__ A, const u16* __restrict__ Bt,
                  const float* __restrict__ bias, void* __restrict__ Cout,
                  int M, int N, int K, int nbn) {
  __shared__ alignas(16) u16 LA[2 * 8192];
  __shared__ alignas(16) u16 LB[3 * 16384];

  const int tid = threadIdx.x;
  const int lane = tid & 63;
  const int wave = tid >> 6;
  const int wm = wave >> 2;
  const int wn = wave & 3;
  const int fr = lane & 15;
  const int kg = lane >> 4;
  const int f7 = fr & 7;
  const int r4 = kg * 4;

  const int nwg = gridDim.x;
  const int swz = (blockIdx.x & 7) * (nwg >> 3) + (blockIdx.x >> 3);
  const int m0 = (swz / nbn) * 128;
  const int n0 = (swz % nbn) * 256;
  const int NT = K >> 6;

  const int srow = tid >> 3;
  const int sgcol = ((tid & 7) ^ (srow & 7)) << 3;
  const size_t aOff = (size_t)(m0 + srow) * K + sgcol;
  const size_t bOff = (size_t)(n0 + srow) * K + sgcol;
  const int ldst = tid * 8;

  auto stageA = [&](int kt, u16* labuf) {
    gload_lds16(A + aOff + (size_t)kt * 64, labuf + ldst);
    gload_lds16(A + aOff + (size_t)64 * K + (size_t)kt * 64, labuf + 4096 + ldst);
  };
  auto stageB = [&](int kt, u16* lbbuf) {
    gload_lds16(Bt + bOff + (size_t)kt * 64, lbbuf + ldst);
    gload_lds16(Bt + bOff + (size_t)64 * K + (size_t)kt * 64, lbbuf + 4096 + ldst);
    gload_lds16(Bt + bOff + (size_t)128 * K + (size_t)kt * 64, lbbuf + 8192 + ldst);
    gload_lds16(Bt + bOff + (size_t)192 * K + (size_t)kt * 64, lbbuf + 12288 + ldst);
  };

  f32x4 acc[4][4] = {};

  stageA(0, LA);
  stageB(0, LB);
  if (NT > 1) {
    stageB(1, LB + 16384);
    asm volatile("s_waitcnt vmcnt(4)" ::: "memory");
  } else {
    asm volatile("s_waitcnt vmcnt(0)" ::: "memory");
  }
  bar();

  for (int kt = 0; kt < NT; ++kt) {
    const bool st1 = (kt + 1 < NT);
    const bool st2 = (kt + 2 < NT);
    u16* laCur = LA + (kt & 1) * 8192;
    u16* lbCur = LB + (kt % 3) * 16384;

    if (st1) stageA(kt + 1, LA + ((kt + 1) & 1) * 8192);
    if (st2) stageB(kt + 2, LB + ((kt + 2) % 3) * 16384);

    bf16x8 aF[4][2], bF[4][2];
#pragma unroll
    for (int m = 0; m < 4; ++m)
#pragma unroll
      for (int ks = 0; ks < 2; ++ks)
        aF[m][ks] = LD8(&laCur[wm * 4096 + (m * 16 + fr) * 64 + (((ks * 4 + kg) ^ f7) << 3)]);
#pragma unroll
    for (int n = 0; n < 4; ++n)
#pragma unroll
      for (int ks = 0; ks < 2; ++ks)
        bF[n][ks] = LD8(&lbCur[wn * 4096 + (n * 16 + fr) * 64 + (((ks * 4 + kg) ^ f7) << 3)]);

    __builtin_amdgcn_s_setprio(1);
#pragma unroll
    for (int ks = 0; ks < 2; ++ks)
#pragma unroll
      for (int m = 0; m < 4; ++m)
#pragma unroll
        for (int n = 0; n < 4; ++n)
          acc[m][n] = mfma16(aF[m][ks], bF[n][ks], acc[m][n]);
    __builtin_amdgcn_s_setprio(0);

    if (st1) {
      if (st2) asm volatile("s_waitcnt vmcnt(4)" ::: "memory");
      else     asm volatile("s_waitcnt vmcnt(0)" ::: "memory");
      bar();
    }
  }

#pragma unroll
  for (int m = 0; m < 4; ++m) {
    const int row = m0 + wm * 64 + m * 16 + r4;
#pragma unroll
    for (int n = 0; n < 4; ++n) {
      const int col = n0 + wn * 64 + n * 16 + fr;
      const float bv = bias[col];
#pragma unroll
      for (int r = 0; r < 4; ++r) {
        float v = acc[m][n][r] + bv;
        size_t off = (size_t)(row + r) * N + col;
        if constexpr (OUT_F32) reinterpret_cast<float*>(Cout)[off] = v;
        else                   reinterpret_cast<u16*>(Cout)[off] = f2bf(v);
      }
    }
  }
}

// ---------------- causal flash attention: 2 waves x 32 q-rows (unchanged, r10) ----------------

__global__ __launch_bounds__(128, 2)
void attn_kernel(const u16* __restrict__ qkv, const u16* __restrict__ vT,
                 u16* __restrict__ obuf) {
  __shared__ alignas(16) u16 Ks[64 * 72];
  __shared__ alignas(16) u16 Vs[64 * 72];
  __shared__ alignas(16) u16 Ps[2][32 * 72];

  const int tid = threadIdx.x;
  const int lane = tid & 63;
  const int wave = tid >> 6;  // 0..1

  const int gid = blockIdx.x;
  const int xcd = gid & 7;
  const int jj = gid >> 3;
  const int g = xcd * 8 + (jj >> 4);
  const int pair = jj & 15;
  const int bb = g >> 4;
  const int h = g & 15;

  const size_t baseQ = (size_t)bb * 2048 * 3072 + h * 64;
  const size_t baseK = baseQ + 1024;
  const size_t baseVt = (size_t)(bb * 16 + h) * 64 * 2048;

  const int fr = lane & 15;
  const int kg8 = (lane >> 4) * 8;
  const int qw32 = wave * 32;
  const int r4 = (lane >> 4) * 4;

  const int rrA = tid >> 3;       // 0..15
  const int cA8 = (tid & 7) * 8;
  const size_t gK = (size_t)rrA * 3072 + cA8;
  const size_t gV = (size_t)rrA * 2048 + cA8;
  const int lof = rrA * 72 + cA8;
  u16* __restrict__ Pw = &Ps[wave][0];

  for (int half = 0; half < 2; ++half) {
    const int qt = half ? (31 - pair) : pair;
    const int q0 = qt * 64;
    const int nt = qt + 1;

    const u16* qrow0 = &qkv[baseQ + (size_t)(q0 + qw32 + fr) * 3072 + kg8];
    bf16x8 aq00 = LD8(qrow0), aq01 = LD8(qrow0 + 32);
    const u16* qrow1 = qrow0 + 16 * 3072;
    bf16x8 aq10 = LD8(qrow1), aq11 = LD8(qrow1 + 32);

    float lsA0 = 0.f, lsA1 = 0.f, lsA2 = 0.f, lsA3 = 0.f;
    float lsB0 = 0.f, lsB1 = 0.f, lsB2 = 0.f, lsB3 = 0.f;
    f32x4 oA0 = {}, oA1 = {}, oA2 = {}, oA3 = {};
    f32x4 oB0 = {}, oB1 = {}, oB2 = {}, oB3 = {};

    uint4 kr0 = LDU4(&qkv[baseK + gK]);
    uint4 kr1 = LDU4(&qkv[baseK + gK + 49152]);
    uint4 kr2 = LDU4(&qkv[baseK + gK + 98304]);
    uint4 kr3 = LDU4(&qkv[baseK + gK + 147456]);
    uint4 vr0 = LDU4(&vT[baseVt + gV]);
    uint4 vr1 = LDU4(&vT[baseVt + gV + 32768]);
    uint4 vr2 = LDU4(&vT[baseVt + gV + 65536]);
    uint4 vr3 = LDU4(&vT[baseVt + gV + 98304]);

    for (int t = 0; t < nt; ++t) {
      __syncthreads();
      *reinterpret_cast<uint4*>(&Ks[lof]) = kr0;
      *reinterpret_cast<uint4*>(&Ks[lof + 1152]) = kr1;
      *reinterpret_cast<uint4*>(&Ks[lof + 2304]) = kr2;
      *reinterpret_cast<uint4*>(&Ks[lof + 3456]) = kr3;
      *reinterpret_cast<uint4*>(&Vs[lof]) = vr0;
      *reinterpret_cast<uint4*>(&Vs[lof + 1152]) = vr1;
      *reinterpret_cast<uint4*>(&Vs[lof + 2304]) = vr2;
      *reinterpret_cast<uint4*>(&Vs[lof + 3456]) = vr3;
      if (t + 1 < nt) {
        const u16* nk = &qkv[baseK + (size_t)(t + 1) * 196608];
        const u16* nv = &vT[baseVt + (size_t)(t + 1) * 64];
        kr0 = LDU4(nk + gK);
        kr1 = LDU4(nk + gK + 49152);
        kr2 = LDU4(nk + gK + 98304);
        kr3 = LDU4(nk + gK + 147456);
        vr0 = LDU4(nv + gV);
        vr1 = LDU4(nv + gV + 32768);
        vr2 = LDU4(nv + gV + 65536);
        vr3 = LDU4(nv + gV + 98304);
      }
      __syncthreads();

      f32x4 sA0 = {}, sA1 = {}, sA2 = {}, sA3 = {};
      f32x4 sB0 = {}, sB1 = {}, sB2 = {}, sB3 = {};
      {
        bf16x8 b;
        __builtin_amdgcn_s_setprio(1);
        b = LD8(&Ks[(fr) * 72 + kg8]);           sA0 = mfma16(aq00, b, sA0); sB0 = mfma16(aq10, b, sB0);
        b = LD8(&Ks[(16 + fr) * 72 + kg8]);      sA1 = mfma16(aq00, b, sA1); sB1 = mfma16(aq10, b, sB1);
        b = LD8(&Ks[(32 + fr) * 72 + kg8]);      sA2 = mfma16(aq00, b, sA2); sB2 = mfma16(aq10, b, sB2);
        b = LD8(&Ks[(48 + fr) * 72 + kg8]);      sA3 = mfma16(aq00, b, sA3); sB3 = mfma16(aq10, b, sB3);
        b = LD8(&Ks[(fr) * 72 + 32 + kg8]);      sA0 = mfma16(aq01, b, sA0); sB0 = mfma16(aq11, b, sB0);
        b = LD8(&Ks[(16 + fr) * 72 + 32 + kg8]); sA1 = mfma16(aq01, b, sA1); sB1 = mfma16(aq11, b, sB1);
        b = LD8(&Ks[(32 + fr) * 72 + 32 + kg8]); sA2 = mfma16(aq01, b, sA2); sB2 = mfma16(aq11, b, sB2);
        b = LD8(&Ks[(48 + fr) * 72 + 32 + kg8]); sA3 = mfma16(aq01, b, sA3); sB3 = mfma16(aq11, b, sB3);
        __builtin_amdgcn_s_setprio(0);
      }

      const bool diag = (t == nt - 1);
#define SM_ROW_G(S0, S1, S2, S3, LS, RB, r)                                    \
      {                                                                        \
        const int qg = qw32 + RB + r4 + r;                                     \
        float p0 = fexp2(S0[r]);                                               \
        float p1 = fexp2(S1[r]);                                               \
        float p2 = fexp2(S2[r]);                                               \
        float p3 = fexp2(S3[r]);                                               \
        if (diag) {                                                            \
          if (fr > qg) p0 = 0.f;                                               \
          if (fr + 16 > qg) p1 = 0.f;                                          \
          if (fr + 32 > qg) p2 = 0.f;                                          \
          if (fr + 48 > qg) p3 = 0.f;                                          \
        }                                                                      \
        LS += (p0 + p1) + (p2 + p3);                                           \
        uint2 w;                                                               \
        w.x = pack2(p0, p1);                                                   \
        w.y = pack2(p2, p3);                                                   \
        *reinterpret_cast<uint2*>(&Pw[(RB + r4 + r) * 72 + fr * 4]) = w;       \
      }
      SM_ROW_G(sA0, sA1, sA2, sA3, lsA0, 0, 0)
      SM_ROW_G(sA0, sA1, sA2, sA3, lsA1, 0, 1)
      SM_ROW_G(sA0, sA1, sA2, sA3, lsA2, 0, 2)
      SM_ROW_G(sA0, sA1, sA2, sA3, lsA3, 0, 3)
      SM_ROW_G(sB0, sB1, sB2, sB3, lsB0, 16, 0)
      SM_ROW_G(sB0, sB1, sB2, sB3, lsB1, 16, 1)
      SM_ROW_G(sB0, sB1, sB2, sB3, lsB2, 16, 2)
      SM_ROW_G(sB0, sB1, sB2, sB3, lsB3, 16, 3)
#undef SM_ROW_G

      {
        bf16x8 pfA = LD8(&Pw[fr * 72 + kg8]);
        bf16x8 pfB = LD8(&Pw[(16 + fr) * 72 + kg8]);
        bf16x8 v;
        __builtin_amdgcn_s_setprio(1);
        v = LD8(&Vs[(fr) * 72 + kg8]);           oA0 = mfma16(pfA, v, oA0); oB0 = mfma16(pfB, v, oB0);
        v = LD8(&Vs[(16 + fr) * 72 + kg8]);      oA1 = mfma16(pfA, v, oA1); oB1 = mfma16(pfB, v, oB1);
        v = LD8(&Vs[(32 + fr) * 72 + kg8]);      oA2 = mfma16(pfA, v, oA2); oB2 = mfma16(pfB, v, oB2);
        v = LD8(&Vs[(48 + fr) * 72 + kg8]);      oA3 = mfma16(pfA, v, oA3); oB3 = mfma16(pfB, v, oB3);
        pfA = LD8(&Pw[fr * 72 + 32 + kg8]);
        pfB = LD8(&Pw[(16 + fr) * 72 + 32 + kg8]);
        v = LD8(&Vs[(fr) * 72 + 32 + kg8]);      oA0 = mfma16(pfA, v, oA0); oB0 = mfma16(pfB, v, oB0);
        v = LD8(&Vs[(16 + fr) * 72 + 32 + kg8]); oA1 = mfma16(pfA, v, oA1); oB1 = mfma16(pfB, v, oB1);
        v = LD8(&Vs[(32 + fr) * 72 + 32 + kg8]); oA2 = mfma16(pfA, v, oA2); oB2 = mfma16(pfB, v, oB2);
        v = LD8(&Vs[(48 + fr) * 72 + 32 + kg8]); oA3 = mfma16(pfA, v, oA3); oB3 = mfma16(pfB, v, oB3);
        __builtin_amdgcn_s_setprio(0);
      }
    }

#define EPI_G(O0, O1, O2, O3, LS, RB, r)                                       \
    {                                                                          \
      float s = LS;                                                            \
      s += __shfl_xor(s, 1);                                                   \
      s += __shfl_xor(s, 2);                                                   \
      s += __shfl_xor(s, 4);                                                   \
      s += __shfl_xor(s, 8);                                                   \
      const float inv = 1.0f / s;                                              \
      const int qg = q0 + qw32 + RB + r4 + r;                                  \
      const size_t rowoff = ((size_t)bb * 2048 + qg) * 1024 + h * 64;          \
      obuf[rowoff + fr] = f2bf(O0[r] * inv);                                   \
      obuf[rowoff + 16 + fr] = f2bf(O1[r] * inv);                              \
      obuf[rowoff + 32 + fr] = f2bf(O2[r] * inv);                              \
      obuf[rowoff + 48 + fr] = f2bf(O3[r] * inv);                              \
    }
    EPI_G(oA0, oA1, oA2, oA3, lsA0, 0, 0)
    EPI_G(oA0, oA1, oA2, oA3, lsA1, 0, 1)
    EPI_G(oA0, oA1, oA2, oA3, lsA2, 0, 2)
    EPI_G(oA0, oA1, oA2, oA3, lsA3, 0, 3)
    EPI_G(oB0, oB1, oB2, oB3, lsB0, 16, 0)
    EPI_G(oB0, oB1, oB2, oB3, lsB1, 16, 1)
    EPI_G(oB0, oB1, oB2, oB3, lsB2, 16, 2)
    EPI_G(oB0, oB1, oB2, oB3, lsB3, 16, 3)
#undef EPI_G
  }
}

// ---------------- launch ----------------

extern "C" void kernel_launch(void* const* d_in, const int* in_sizes, int n_in,
                              void* d_out, int out_size, void* d_ws, size_t ws_size,
                              hipStream_t stream) {
  const float* x  = (const float*)d_in[0];
  const float* Wq = (const float*)d_in[1];
  const float* bq = (const float*)d_in[2];
  const float* Wk = (const float*)d_in[3];
  const float* bk = (const float*)d_in[4];
  const float* Wv = (const float*)d_in[5];
  const float* bv = (const float*)d_in[6];
  const float* Wp = (const float*)d_in[7];
  const float* bp = (const float*)d_in[8];

  char* ws = (char*)d_ws;
  size_t off = 0;
  auto alloc = [&](size_t bytes) -> void* {
    void* p = ws + off;
    off += (bytes + 255) & ~(size_t)255;
    return p;
  };
  u16*   xb     = (u16*)  alloc((size_t)8192 * 1024 * 2);  // reused as vT after QKV GEMM
  u16*   wqkv_t = (u16*)  alloc((size_t)3072 * 1024 * 2);
  float* biasq  = (float*)alloc((size_t)3072 * 4);
  u16*   wpt    = (u16*)  alloc((size_t)1024 * 1024 * 2);
  u16*   qkv    = (u16*)  alloc((size_t)8192 * 3072 * 2);
  u16*   obuf   = (u16*)  alloc((size_t)8192 * 1024 * 2);
  u16*   vT     = xb;  // xb is dead after the QKV GEMM; vT is exactly 16 MB too
  (void)ws_size; (void)in_sizes; (void)n_in; (void)out_size;

  cvt_x_kernel<<<2048, 256, 0, stream>>>(x, xb, 8192 * 1024 / 8);
  cvt_wqkv_kernel<<<dim3(16, 16, 3), 256, 0, stream>>>(Wq, Wk, Wv, bq, bk, bv, wqkv_t, biasq);
  cvt_wp_kernel<<<dim3(16, 16), 256, 0, stream>>>(Wp, wpt);
  gemm12_kernel<false><<<384, 512, 0, stream>>>(xb, wqkv_t, biasq, qkv, 8192, 3072, 1024, 12);
  transpose_v_kernel<<<dim3(32, 16, 4), 256, 0, stream>>>(qkv, vT);
  attn_kernel<<<1024, 128, 0, stream>>>(qkv, vT, obuf);
  gemm9_kernel<true><<<256, 512, 0, stream>>>(obuf, wpt, bp, d_out, 8192, 1024, 1024, 4);
}

// Round 13
// 162.383 us; speedup vs baseline: 1.0579x; 1.0096x over previous
//
#include <hip/hip_runtime.h>
#include <hip/hip_bf16.h>
#include <stdint.h>

// B=4, T=2048, C=1024, H=16, hd=64
// qkv bf16 [8192][3072] (cols: 0..1023=Q, 1024..2047=K, 2048..3071=V; within: h*64+d)
//   NOTE: Wq/bq are pre-scaled by log2(e)/32, so softmax = exp2(S).
// vT bf16 [(bb*16+h)*64+d][2048]: sigma-permuted per 64-token tile.
// GEMMs: gemm13 = 128x256 tile, BK=32, A/B dbuf 48KB LDS -> 2+ blocks/CU (TLP hides the
//   per-K-tile drain), stage-ahead-1, row-XOR swizzle (2-way free), XCD swizzle, setprio.
// attn: r10-verified 2 waves x 32 q-rows.

typedef unsigned short u16;
typedef __attribute__((ext_vector_type(4))) float f32x4;
typedef __attribute__((ext_vector_type(8))) __bf16 bf16x8;
typedef __attribute__((ext_vector_type(2))) __bf16 bf16x2;

#define DEV static __device__ __forceinline__

DEV u16 f2bf(float f) {  // RNE float->bf16 (finite inputs only)
  uint32_t u = __builtin_bit_cast(uint32_t, f);
  return (u16)((u + 0x7FFFu + ((u >> 16) & 1u)) >> 16);
}

DEV uint pack2(float a, float b) {  // v_cvt_pk_bf16_f32 via vector of casts
  bf16x2 v;
  v.x = (__bf16)a;
  v.y = (__bf16)b;
  return __builtin_bit_cast(uint, v);
}

#if __has_builtin(__builtin_amdgcn_exp2f)
DEV float fexp2(float x) { return __builtin_amdgcn_exp2f(x); }
#else
DEV float fexp2(float x) { return __expf(x * 0.69314718056f); }
#endif

DEV void gload_lds16(const void* g, void* lds) {  // 16B/lane global->LDS direct
  auto gp = reinterpret_cast<const __attribute__((address_space(1))) uint32_t*>(
      reinterpret_cast<uintptr_t>(g));
  auto lp = reinterpret_cast<__attribute__((address_space(3))) uint32_t*>(
      static_cast<uint32_t>(reinterpret_cast<uintptr_t>(lds)));
  __builtin_amdgcn_global_load_lds(gp, lp, 16, 0, 0);
}

DEV f32x4 mfma16(bf16x8 a, bf16x8 b, f32x4 c) {
  return __builtin_amdgcn_mfma_f32_16x16x32_bf16(a, b, c, 0, 0, 0);
}

DEV void bar() {  // raw s_barrier + compiler memory fence
  asm volatile("" ::: "memory");
  __builtin_amdgcn_s_barrier();
  asm volatile("" ::: "memory");
}

#define LD8(p) (*reinterpret_cast<const bf16x8*>(p))
#define LDU4(p) (*reinterpret_cast<const uint4*>(p))

// ---------------- conversion kernels ----------------

__global__ void cvt_x_kernel(const float* __restrict__ x, u16* __restrict__ xb, int n8) {
  int i = blockIdx.x * blockDim.x + threadIdx.x;
  int stride = gridDim.x * blockDim.x;
  for (; i < n8; i += stride) {
    const float4* xp = reinterpret_cast<const float4*>(x) + 2 * (size_t)i;
    float4 a = xp[0], b = xp[1];
    uint4 o;
    o.x = pack2(a.x, a.y);
    o.y = pack2(a.z, a.w);
    o.z = pack2(b.x, b.y);
    o.w = pack2(b.z, b.w);
    reinterpret_cast<uint4*>(xb)[i] = o;
  }
}

// Wq/Wk/Wv [16][1024][64] -> wt[n=which*1024+h*64+d][c] (bf16), biasq[n].
__global__ void cvt_wqkv_kernel(const float* __restrict__ Wq, const float* __restrict__ Wk,
                                const float* __restrict__ Wv, const float* __restrict__ bq,
                                const float* __restrict__ bk, const float* __restrict__ bv,
                                u16* __restrict__ wt, float* __restrict__ biasq) {
  __shared__ u16 tle[64 * 72];
  const int tid = threadIdx.x;
  const int ct = blockIdx.x;     // c-tile 0..15
  const int h = blockIdx.y;      // 0..15
  const int which = blockIdx.z;  // 0..2
  const float* W = (which == 0) ? Wq : (which == 1) ? Wk : Wv;
  const float* Bb = (which == 0) ? bq : (which == 1) ? bk : bv;
  const float scl = (which == 0) ? 0.045084220027780106f : 1.0f;  // log2(e)/32
#pragma unroll
  for (int i = 0; i < 4; ++i) {
    int idx = i * 256 + tid;
    int c_l = idx >> 4, d4 = (idx & 15) * 4;
    float4 v = *reinterpret_cast<const float4*>(&W[((size_t)(h * 1024 + ct * 64 + c_l)) * 64 + d4]);
    tle[(d4 + 0) * 72 + c_l] = f2bf(v.x * scl);
    tle[(d4 + 1) * 72 + c_l] = f2bf(v.y * scl);
    tle[(d4 + 2) * 72 + c_l] = f2bf(v.z * scl);
    tle[(d4 + 3) * 72 + c_l] = f2bf(v.w * scl);
  }
  __syncthreads();
#pragma unroll
  for (int i = 0; i < 2; ++i) {
    int idx = i * 256 + tid;
    int d_o = idx >> 3, c8 = (idx & 7) * 8;
    uint4 v = LDU4(&tle[d_o * 72 + c8]);
    *reinterpret_cast<uint4*>(&wt[(size_t)(which * 1024 + h * 64 + d_o) * 1024 + ct * 64 + c8]) = v;
  }
  if (ct == 0 && tid < 64) biasq[which * 1024 + h * 64 + tid] = Bb[h * 64 + tid] * scl;
}

// Wp [1024][1024] -> wpt[n][c] = Wp[c][n]
__global__ void cvt_wp_kernel(const float* __restrict__ Wp, u16* __restrict__ wpt) {
  __shared__ u16 tle[64 * 72];
  const int tid = threadIdx.x;
  const int ct = blockIdx.x;
  const int nt = blockIdx.y;
#pragma unroll
  for (int i = 0; i < 4; ++i) {
    int idx = i * 256 + tid;
    int c_l = idx >> 4, n4 = (idx & 15) * 4;
    float4 v = *reinterpret_cast<const float4*>(&Wp[(size_t)(ct * 64 + c_l) * 1024 + nt * 64 + n4]);
    tle[(n4 + 0) * 72 + c_l] = f2bf(v.x);
    tle[(n4 + 1) * 72 + c_l] = f2bf(v.y);
    tle[(n4 + 2) * 72 + c_l] = f2bf(v.z);
    tle[(n4 + 3) * 72 + c_l] = f2bf(v.w);
  }
  __syncthreads();
#pragma unroll
  for (int i = 0; i < 2; ++i) {
    int idx = i * 256 + tid;
    int n_o = idx >> 3, c8 = (idx & 7) * 8;
    uint4 v = LDU4(&tle[n_o * 72 + c8]);
    *reinterpret_cast<uint4*>(&wpt[(size_t)(nt * 64 + n_o) * 1024 + ct * 64 + c8]) = v;
  }
}

// qkv V-part -> vT[(bb*16+h)*64+d][2048], sigma-permuted per 64-token tile.
__global__ __launch_bounds__(256)
void transpose_v_kernel(const u16* __restrict__ qkv, u16* __restrict__ vT) {
  __shared__ alignas(16) u16 tle[64 * 72];
  const int tid = threadIdx.x;
  const int tt = blockIdx.x;  // token tile 0..31
  const int h = blockIdx.y;   // 0..15
  const int bb = blockIdx.z;  // 0..3
  const size_t rbase = ((size_t)bb * 2048 + tt * 64) * 3072 + 2048 + h * 64;
#pragma unroll
  for (int i = 0; i < 2; ++i) {
    int idx = i * 256 + tid;  // 0..511
    int s = idx >> 3, c8 = (idx & 7) * 8;
    *reinterpret_cast<uint4*>(&tle[s * 72 + c8]) = LDU4(&qkv[rbase + (size_t)s * 3072 + c8]);
  }
  __syncthreads();
#pragma unroll
  for (int i = 0; i < 2; ++i) {
    int idx = i * 256 + tid;
    int d = idx >> 3, cb = idx & 7;
    uint4 o;
    o.x = (uint)tle[(2 * cb + 0) * 72 + d] | ((uint)tle[(16 + 2 * cb + 0) * 72 + d] << 16);
    o.y = (uint)tle[(32 + 2 * cb + 0) * 72 + d] | ((uint)tle[(48 + 2 * cb + 0) * 72 + d] << 16);
    o.z = (uint)tle[(2 * cb + 1) * 72 + d] | ((uint)tle[(16 + 2 * cb + 1) * 72 + d] << 16);
    o.w = (uint)tle[(32 + 2 * cb + 1) * 72 + d] | ((uint)tle[(48 + 2 * cb + 1) * 72 + d] << 16);
    *reinterpret_cast<uint4*>(
        &vT[((size_t)(bb * 16 + h) * 64 + d) * 2048 + tt * 64 + cb * 8]) = o;
  }
}

// ---------------- gemm13: 128x256, BK=32, 48KB LDS -> 2+ blocks/CU ----------------
// 8 waves (2M x 4N), wave tile 64x64 (acc[4][4]). A dbuf 2x8KB, B dbuf 2x16KB.
// Stage-ahead-1 (3 gloads/K-tile) into the other buffer (readers drained at prior
// barrier -> WAR-free); one vmcnt(0)+s_barrier per K-tile, hidden by the co-resident
// block (2 blocks/CU). Swizzle: 64B LDS rows; slot s_lds = kg ^ ((row>>1)&3) both
// sides -> 2-way bank aliasing (free). K-order identical to gemm9 (bit-identical C).

template <bool OUT_F32>
__global__ __launch_bounds__(512, 4)
void gemm13_kernel(const u16* __restrict__ A, const u16* __restrict__ Bt,
                   const float* __restrict__ bias, void* __restrict__ Cout,
                   int M, int N, int K, int nbn) {
  __shared__ alignas(16) u16 LA[2 * 4096];  // 2 x (128x32) = 16 KB
  __shared__ alignas(16) u16 LB[2 * 8192];  // 2 x (256x32) = 32 KB

  const int tid = threadIdx.x;
  const int lane = tid & 63;
  const int wave = tid >> 6;   // 0..7
  const int wm = wave >> 2;    // 0..1
  const int wn = wave & 3;     // 0..3
  const int fr = lane & 15;
  const int kg = lane >> 4;    // 0..3 (16B k-slot)
  const int r4 = kg * 4;

  const int nwg = gridDim.x;  // multiple of 8
  const int swz = (blockIdx.x & 7) * (nwg >> 3) + (blockIdx.x >> 3);
  const int m0 = (swz / nbn) * 128;
  const int n0 = (swz % nbn) * 256;
  const int NT = K >> 5;

  // staging: thread covers LDS 16B chunk (row tid>>2, slot tid&3); global source
  // col-slot inverse-swizzled: g = (tid&3) ^ ((row>>1)&3).
  const int srow = tid >> 2;  // 0..127
  const int sgcol = (((tid & 3) ^ ((srow >> 1) & 3)) << 3);  // u16 offset
  const size_t aOff = (size_t)(m0 + srow) * K + sgcol;
  const size_t bOff = (size_t)(n0 + srow) * K + sgcol;
  const int ldst = tid * 8;  // u16 (16B per thread, linear per wave)

  auto stageA = [&](int kt, u16* d) {  // 128 rows x 32 cols = 8KB = 1 gload
    gload_lds16(A + aOff + (size_t)kt * 32, d + ldst);
  };
  auto stageB = [&](int kt, u16* d) {  // 256 rows = 2 gloads
    gload_lds16(Bt + bOff + (size_t)kt * 32, d + ldst);
    gload_lds16(Bt + bOff + (size_t)128 * K + (size_t)kt * 32, d + 4096 + ldst);
  };

  f32x4 acc[4][4] = {};

  stageA(0, LA);
  stageB(0, LB);
  asm volatile("s_waitcnt vmcnt(0)" ::: "memory");
  bar();

  for (int kt = 0; kt < NT; ++kt) {
    const bool st1 = (kt + 1 < NT);
    u16* la = LA + (kt & 1) * 4096;
    u16* lb = LB + (kt & 1) * 8192;

    if (st1) {
      stageA(kt + 1, LA + ((kt + 1) & 1) * 4096);
      stageB(kt + 1, LB + ((kt + 1) & 1) * 8192);
    }

    bf16x8 aF[4], bF[4];
#pragma unroll
    for (int m = 0; m < 4; ++m) {
      const int R = wm * 64 + m * 16 + fr;
      aF[m] = LD8(&la[R * 32 + ((kg ^ ((R >> 1) & 3)) << 3)]);
    }
#pragma unroll
    for (int n = 0; n < 4; ++n) {
      const int R = wn * 64 + n * 16 + fr;
      bF[n] = LD8(&lb[R * 32 + ((kg ^ ((R >> 1) & 3)) << 3)]);
    }

    __builtin_amdgcn_s_setprio(1);
#pragma unroll
    for (int m = 0; m < 4; ++m)
#pragma unroll
      for (int n = 0; n < 4; ++n)
        acc[m][n] = mfma16(aF[m], bF[n], acc[m][n]);
    __builtin_amdgcn_s_setprio(0);

    if (st1) {
      asm volatile("s_waitcnt vmcnt(0)" ::: "memory");
      bar();
    }
  }

  // epilogue
#pragma unroll
  for (int m = 0; m < 4; ++m) {
    const int row = m0 + wm * 64 + m * 16 + r4;
#pragma unroll
    for (int n = 0; n < 4; ++n) {
      const int col = n0 + wn * 64 + n * 16 + fr;
      const float bv = bias[col];
#pragma unroll
      for (int r = 0; r < 4; ++r) {
        float v = acc[m][n][r] + bv;
        size_t off = (size_t)(row + r) * N + col;
        if constexpr (OUT_F32) reinterpret_cast<float*>(Cout)[off] = v;
        else                   reinterpret_cast<u16*>(Cout)[off] = f2bf(v);
      }
    }
  }
}

// ---------------- causal flash attention: 2 waves x 32 q-rows (unchanged, r10) ----------------

__global__ __launch_bounds__(128, 2)
void attn_kernel(const u16* __restrict__ qkv, const u16* __restrict__ vT,
                 u16* __restrict__ obuf) {
  __shared__ alignas(16) u16 Ks[64 * 72];
  __shared__ alignas(16) u16 Vs[64 * 72];
  __shared__ alignas(16) u16 Ps[2][32 * 72];

  const int tid = threadIdx.x;
  const int lane = tid & 63;
  const int wave = tid >> 6;  // 0..1

  const int gid = blockIdx.x;
  const int xcd = gid & 7;
  const int jj = gid >> 3;
  const int g = xcd * 8 + (jj >> 4);
  const int pair = jj & 15;
  const int bb = g >> 4;
  const int h = g & 15;

  const size_t baseQ = (size_t)bb * 2048 * 3072 + h * 64;
  const size_t baseK = baseQ + 1024;
  const size_t baseVt = (size_t)(bb * 16 + h) * 64 * 2048;

  const int fr = lane & 15;
  const int kg8 = (lane >> 4) * 8;
  const int qw32 = wave * 32;
  const int r4 = (lane >> 4) * 4;

  const int rrA = tid >> 3;       // 0..15
  const int cA8 = (tid & 7) * 8;
  const size_t gK = (size_t)rrA * 3072 + cA8;
  const size_t gV = (size_t)rrA * 2048 + cA8;
  const int lof = rrA * 72 + cA8;
  u16* __restrict__ Pw = &Ps[wave][0];

  for (int half = 0; half < 2; ++half) {
    const int qt = half ? (31 - pair) : pair;
    const int q0 = qt * 64;
    const int nt = qt + 1;

    const u16* qrow0 = &qkv[baseQ + (size_t)(q0 + qw32 + fr) * 3072 + kg8];
    bf16x8 aq00 = LD8(qrow0), aq01 = LD8(qrow0 + 32);
    const u16* qrow1 = qrow0 + 16 * 3072;
    bf16x8 aq10 = LD8(qrow1), aq11 = LD8(qrow1 + 32);

    float lsA0 = 0.f, lsA1 = 0.f, lsA2 = 0.f, lsA3 = 0.f;
    float lsB0 = 0.f, lsB1 = 0.f, lsB2 = 0.f, lsB3 = 0.f;
    f32x4 oA0 = {}, oA1 = {}, oA2 = {}, oA3 = {};
    f32x4 oB0 = {}, oB1 = {}, oB2 = {}, oB3 = {};

    uint4 kr0 = LDU4(&qkv[baseK + gK]);
    uint4 kr1 = LDU4(&qkv[baseK + gK + 49152]);
    uint4 kr2 = LDU4(&qkv[baseK + gK + 98304]);
    uint4 kr3 = LDU4(&qkv[baseK + gK + 147456]);
    uint4 vr0 = LDU4(&vT[baseVt + gV]);
    uint4 vr1 = LDU4(&vT[baseVt + gV + 32768]);
    uint4 vr2 = LDU4(&vT[baseVt + gV + 65536]);
    uint4 vr3 = LDU4(&vT[baseVt + gV + 98304]);

    for (int t = 0; t < nt; ++t) {
      __syncthreads();
      *reinterpret_cast<uint4*>(&Ks[lof]) = kr0;
      *reinterpret_cast<uint4*>(&Ks[lof + 1152]) = kr1;
      *reinterpret_cast<uint4*>(&Ks[lof + 2304]) = kr2;
      *reinterpret_cast<uint4*>(&Ks[lof + 3456]) = kr3;
      *reinterpret_cast<uint4*>(&Vs[lof]) = vr0;
      *reinterpret_cast<uint4*>(&Vs[lof + 1152]) = vr1;
      *reinterpret_cast<uint4*>(&Vs[lof + 2304]) = vr2;
      *reinterpret_cast<uint4*>(&Vs[lof + 3456]) = vr3;
      if (t + 1 < nt) {
        const u16* nk = &qkv[baseK + (size_t)(t + 1) * 196608];
        const u16* nv = &vT[baseVt + (size_t)(t + 1) * 64];
        kr0 = LDU4(nk + gK);
        kr1 = LDU4(nk + gK + 49152);
        kr2 = LDU4(nk + gK + 98304);
        kr3 = LDU4(nk + gK + 147456);
        vr0 = LDU4(nv + gV);
        vr1 = LDU4(nv + gV + 32768);
        vr2 = LDU4(nv + gV + 65536);
        vr3 = LDU4(nv + gV + 98304);
      }
      __syncthreads();

      f32x4 sA0 = {}, sA1 = {}, sA2 = {}, sA3 = {};
      f32x4 sB0 = {}, sB1 = {}, sB2 = {}, sB3 = {};
      {
        bf16x8 b;
        __builtin_amdgcn_s_setprio(1);
        b = LD8(&Ks[(fr) * 72 + kg8]);           sA0 = mfma16(aq00, b, sA0); sB0 = mfma16(aq10, b, sB0);
        b = LD8(&Ks[(16 + fr) * 72 + kg8]);      sA1 = mfma16(aq00, b, sA1); sB1 = mfma16(aq10, b, sB1);
        b = LD8(&Ks[(32 + fr) * 72 + kg8]);      sA2 = mfma16(aq00, b, sA2); sB2 = mfma16(aq10, b, sB2);
        b = LD8(&Ks[(48 + fr) * 72 + kg8]);      sA3 = mfma16(aq00, b, sA3); sB3 = mfma16(aq10, b, sB3);
        b = LD8(&Ks[(fr) * 72 + 32 + kg8]);      sA0 = mfma16(aq01, b, sA0); sB0 = mfma16(aq11, b, sB0);
        b = LD8(&Ks[(16 + fr) * 72 + 32 + kg8]); sA1 = mfma16(aq01, b, sA1); sB1 = mfma16(aq11, b, sB1);
        b = LD8(&Ks[(32 + fr) * 72 + 32 + kg8]); sA2 = mfma16(aq01, b, sA2); sB2 = mfma16(aq11, b, sB2);
        b = LD8(&Ks[(48 + fr) * 72 + 32 + kg8]); sA3 = mfma16(aq01, b, sA3); sB3 = mfma16(aq11, b, sB3);
        __builtin_amdgcn_s_setprio(0);
      }

      const bool diag = (t == nt - 1);
#define SM_ROW_G(S0, S1, S2, S3, LS, RB, r)                                    \
      {                                                                        \
        const int qg = qw32 + RB + r4 + r;                                     \
        float p0 = fexp2(S0[r]);                                               \
        float p1 = fexp2(S1[r]);                                               \
        float p2 = fexp2(S2[r]);                                               \
        float p3 = fexp2(S3[r]);                                               \
        if (diag) {                                                            \
          if (fr > qg) p0 = 0.f;                                               \
          if (fr + 16 > qg) p1 = 0.f;                                          \
          if (fr + 32 > qg) p2 = 0.f;                                          \
          if (fr + 48 > qg) p3 = 0.f;                                          \
        }                                                                      \
        LS += (p0 + p1) + (p2 + p3);                                           \
        uint2 w;                                                               \
        w.x = pack2(p0, p1);                                                   \
        w.y = pack2(p2, p3);                                                   \
        *reinterpret_cast<uint2*>(&Pw[(RB + r4 + r) * 72 + fr * 4]) = w;       \
      }
      SM_ROW_G(sA0, sA1, sA2, sA3, lsA0, 0, 0)
      SM_ROW_G(sA0, sA1, sA2, sA3, lsA1, 0, 1)
      SM_ROW_G(sA0, sA1, sA2, sA3, lsA2, 0, 2)
      SM_ROW_G(sA0, sA1, sA2, sA3, lsA3, 0, 3)
      SM_ROW_G(sB0, sB1, sB2, sB3, lsB0, 16, 0)
      SM_ROW_G(sB0, sB1, sB2, sB3, lsB1, 16, 1)
      SM_ROW_G(sB0, sB1, sB2, sB3, lsB2, 16, 2)
      SM_ROW_G(sB0, sB1, sB2, sB3, lsB3, 16, 3)
#undef SM_ROW_G

      {
        bf16x8 pfA = LD8(&Pw[fr * 72 + kg8]);
        bf16x8 pfB = LD8(&Pw[(16 + fr) * 72 + kg8]);
        bf16x8 v;
        __builtin_amdgcn_s_setprio(1);
        v = LD8(&Vs[(fr) * 72 + kg8]);           oA0 = mfma16(pfA, v, oA0); oB0 = mfma16(pfB, v, oB0);
        v = LD8(&Vs[(16 + fr) * 72 + kg8]);      oA1 = mfma16(pfA, v, oA1); oB1 = mfma16(pfB, v, oB1);
        v = LD8(&Vs[(32 + fr) * 72 + kg8]);      oA2 = mfma16(pfA, v, oA2); oB2 = mfma16(pfB, v, oB2);
        v = LD8(&Vs[(48 + fr) * 72 + kg8]);      oA3 = mfma16(pfA, v, oA3); oB3 = mfma16(pfB, v, oB3);
        pfA = LD8(&Pw[fr * 72 + 32 + kg8]);
        pfB = LD8(&Pw[(16 + fr) * 72 + 32 + kg8]);
        v = LD8(&Vs[(fr) * 72 + 32 + kg8]);      oA0 = mfma16(pfA, v, oA0); oB0 = mfma16(pfB, v, oB0);
        v = LD8(&Vs[(16 + fr) * 72 + 32 + kg8]); oA1 = mfma16(pfA, v, oA1); oB1 = mfma16(pfB, v, oB1);
        v = LD8(&Vs[(32 + fr) * 72 + 32 + kg8]); oA2 = mfma16(pfA, v, oA2); oB2 = mfma16(pfB, v, oB2);
        v = LD8(&Vs[(48 + fr) * 72 + 32 + kg8]); oA3 = mfma16(pfA, v, oA3); oB3 = mfma16(pfB, v, oB3);
        __builtin_amdgcn_s_setprio(0);
      }
    }

#define EPI_G(O0, O1, O2, O3, LS, RB, r)                                       \
    {                                                                          \
      float s = LS;                                                            \
      s += __shfl_xor(s, 1);                                                   \
      s += __shfl_xor(s, 2);                                                   \
      s += __shfl_xor(s, 4);                                                   \
      s += __shfl_xor(s, 8);                                                   \
      const float inv = 1.0f / s;                                              \
      const int qg = q0 + qw32 + RB + r4 + r;                                  \
      const size_t rowoff = ((size_t)bb * 2048 + qg) * 1024 + h * 64;          \
      obuf[rowoff + fr] = f2bf(O0[r] * inv);                                   \
      obuf[rowoff + 16 + fr] = f2bf(O1[r] * inv);                              \
      obuf[rowoff + 32 + fr] = f2bf(O2[r] * inv);                              \
      obuf[rowoff + 48 + fr] = f2bf(O3[r] * inv);                              \
    }
    EPI_G(oA0, oA1, oA2, oA3, lsA0, 0, 0)
    EPI_G(oA0, oA1, oA2, oA3, lsA1, 0, 1)
    EPI_G(oA0, oA1, oA2, oA3, lsA2, 0, 2)
    EPI_G(oA0, oA1, oA2, oA3, lsA3, 0, 3)
    EPI_G(oB0, oB1, oB2, oB3, lsB0, 16, 0)
    EPI_G(oB0, oB1, oB2, oB3, lsB1, 16, 1)
    EPI_G(oB0, oB1, oB2, oB3, lsB2, 16, 2)
    EPI_G(oB0, oB1, oB2, oB3, lsB3, 16, 3)
#undef EPI_G
  }
}

// ---------------- launch ----------------

extern "C" void kernel_launch(void* const* d_in, const int* in_sizes, int n_in,
                              void* d_out, int out_size, void* d_ws, size_t ws_size,
                              hipStream_t stream) {
  const float* x  = (const float*)d_in[0];
  const float* Wq = (const float*)d_in[1];
  const float* bq = (const float*)d_in[2];
  const float* Wk = (const float*)d_in[3];
  const float* bk = (const float*)d_in[4];
  const float* Wv = (const float*)d_in[5];
  const float* bv = (const float*)d_in[6];
  const float* Wp = (const float*)d_in[7];
  const float* bp = (const float*)d_in[8];

  char* ws = (char*)d_ws;
  size_t off = 0;
  auto alloc = [&](size_t bytes) -> void* {
    void* p = ws + off;
    off += (bytes + 255) & ~(size_t)255;
    return p;
  };
  u16*   xb     = (u16*)  alloc((size_t)8192 * 1024 * 2);  // reused as vT after QKV GEMM
  u16*   wqkv_t = (u16*)  alloc((size_t)3072 * 1024 * 2);
  float* biasq  = (float*)alloc((size_t)3072 * 4);
  u16*   wpt    = (u16*)  alloc((size_t)1024 * 1024 * 2);
  u16*   qkv    = (u16*)  alloc((size_t)8192 * 3072 * 2);
  u16*   obuf   = (u16*)  alloc((size_t)8192 * 1024 * 2);
  u16*   vT     = xb;  // xb is dead after the QKV GEMM; vT is exactly 16 MB too
  (void)ws_size; (void)in_sizes; (void)n_in; (void)out_size;

  cvt_x_kernel<<<2048, 256, 0, stream>>>(x, xb, 8192 * 1024 / 8);
  cvt_wqkv_kernel<<<dim3(16, 16, 3), 256, 0, stream>>>(Wq, Wk, Wv, bq, bk, bv, wqkv_t, biasq);
  cvt_wp_kernel<<<dim3(16, 16), 256, 0, stream>>>(Wp, wpt);
  gemm13_kernel<false><<<768, 512, 0, stream>>>(xb, wqkv_t, biasq, qkv, 8192, 3072, 1024, 12);
  transpose_v_kernel<<<dim3(32, 16, 4), 256, 0, stream>>>(qkv, vT);
  attn_kernel<<<1024, 128, 0, stream>>>(qkv, vT, obuf);
  gemm13_kernel<true><<<256, 512, 0, stream>>>(obuf, wpt, bp, d_out, 8192, 1024, 1024, 4);
}

// Round 14
// 158.150 us; speedup vs baseline: 1.0862x; 1.0268x over previous
//
#include <hip/hip_runtime.h>
#include <hip/hip_bf16.h>
#include <stdint.h>

// B=4, T=2048, C=1024, H=16, hd=64
// qkv bf16 [8192][3072] (cols: 0..1023=Q, 1024..2047=K, 2048..3071=V; within: h*64+d)
//   NOTE: Wq/bq are pre-scaled by log2(e)/32, so softmax = exp2(S).
// vT bf16 [(bb*16+h)*64+d][2048]: sigma-permuted per 64-token tile.
// QKV GEMM: gemm13 (128x256, BK=32, 48KB LDS, 3 blocks/CU TLP) — r13-measured 66.6us.
// proj GEMM: gemm9 (128x256, BK=64, A-dbuf+B-tribuf, counted vmcnt) — r10-measured ~14us
//   (gemm13 at 1 block/CU exposed its 32 drains; structure choice is occupancy-dependent).
// attn: r10-verified 2 waves x 32 q-rows.

typedef unsigned short u16;
typedef __attribute__((ext_vector_type(4))) float f32x4;
typedef __attribute__((ext_vector_type(8))) __bf16 bf16x8;
typedef __attribute__((ext_vector_type(2))) __bf16 bf16x2;

#define DEV static __device__ __forceinline__

DEV u16 f2bf(float f) {  // RNE float->bf16 (finite inputs only)
  uint32_t u = __builtin_bit_cast(uint32_t, f);
  return (u16)((u + 0x7FFFu + ((u >> 16) & 1u)) >> 16);
}

DEV uint pack2(float a, float b) {  // v_cvt_pk_bf16_f32 via vector of casts
  bf16x2 v;
  v.x = (__bf16)a;
  v.y = (__bf16)b;
  return __builtin_bit_cast(uint, v);
}

#if __has_builtin(__builtin_amdgcn_exp2f)
DEV float fexp2(float x) { return __builtin_amdgcn_exp2f(x); }
#else
DEV float fexp2(float x) { return __expf(x * 0.69314718056f); }
#endif

DEV void gload_lds16(const void* g, void* lds) {  // 16B/lane global->LDS direct
  auto gp = reinterpret_cast<const __attribute__((address_space(1))) uint32_t*>(
      reinterpret_cast<uintptr_t>(g));
  auto lp = reinterpret_cast<__attribute__((address_space(3))) uint32_t*>(
      static_cast<uint32_t>(reinterpret_cast<uintptr_t>(lds)));
  __builtin_amdgcn_global_load_lds(gp, lp, 16, 0, 0);
}

DEV f32x4 mfma16(bf16x8 a, bf16x8 b, f32x4 c) {
  return __builtin_amdgcn_mfma_f32_16x16x32_bf16(a, b, c, 0, 0, 0);
}

DEV void bar() {  // raw s_barrier + compiler memory fence
  asm volatile("" ::: "memory");
  __builtin_amdgcn_s_barrier();
  asm volatile("" ::: "memory");
}

#define LD8(p) (*reinterpret_cast<const bf16x8*>(p))
#define LDU4(p) (*reinterpret_cast<const uint4*>(p))

// ---------------- conversion kernels ----------------

__global__ void cvt_x_kernel(const float* __restrict__ x, u16* __restrict__ xb, int n8) {
  int i = blockIdx.x * blockDim.x + threadIdx.x;
  int stride = gridDim.x * blockDim.x;
  for (; i < n8; i += stride) {
    const float4* xp = reinterpret_cast<const float4*>(x) + 2 * (size_t)i;
    float4 a = xp[0], b = xp[1];
    uint4 o;
    o.x = pack2(a.x, a.y);
    o.y = pack2(a.z, a.w);
    o.z = pack2(b.x, b.y);
    o.w = pack2(b.z, b.w);
    reinterpret_cast<uint4*>(xb)[i] = o;
  }
}

// Wq/Wk/Wv [16][1024][64] -> wt[n=which*1024+h*64+d][c] (bf16), biasq[n].
__global__ void cvt_wqkv_kernel(const float* __restrict__ Wq, const float* __restrict__ Wk,
                                const float* __restrict__ Wv, const float* __restrict__ bq,
                                const float* __restrict__ bk, const float* __restrict__ bv,
                                u16* __restrict__ wt, float* __restrict__ biasq) {
  __shared__ u16 tle[64 * 72];
  const int tid = threadIdx.x;
  const int ct = blockIdx.x;     // c-tile 0..15
  const int h = blockIdx.y;      // 0..15
  const int which = blockIdx.z;  // 0..2
  const float* W = (which == 0) ? Wq : (which == 1) ? Wk : Wv;
  const float* Bb = (which == 0) ? bq : (which == 1) ? bk : bv;
  const float scl = (which == 0) ? 0.045084220027780106f : 1.0f;  // log2(e)/32
#pragma unroll
  for (int i = 0; i < 4; ++i) {
    int idx = i * 256 + tid;
    int c_l = idx >> 4, d4 = (idx & 15) * 4;
    float4 v = *reinterpret_cast<const float4*>(&W[((size_t)(h * 1024 + ct * 64 + c_l)) * 64 + d4]);
    tle[(d4 + 0) * 72 + c_l] = f2bf(v.x * scl);
    tle[(d4 + 1) * 72 + c_l] = f2bf(v.y * scl);
    tle[(d4 + 2) * 72 + c_l] = f2bf(v.z * scl);
    tle[(d4 + 3) * 72 + c_l] = f2bf(v.w * scl);
  }
  __syncthreads();
#pragma unroll
  for (int i = 0; i < 2; ++i) {
    int idx = i * 256 + tid;
    int d_o = idx >> 3, c8 = (idx & 7) * 8;
    uint4 v = LDU4(&tle[d_o * 72 + c8]);
    *reinterpret_cast<uint4*>(&wt[(size_t)(which * 1024 + h * 64 + d_o) * 1024 + ct * 64 + c8]) = v;
  }
  if (ct == 0 && tid < 64) biasq[which * 1024 + h * 64 + tid] = Bb[h * 64 + tid] * scl;
}

// Wp [1024][1024] -> wpt[n][c] = Wp[c][n]
__global__ void cvt_wp_kernel(const float* __restrict__ Wp, u16* __restrict__ wpt) {
  __shared__ u16 tle[64 * 72];
  const int tid = threadIdx.x;
  const int ct = blockIdx.x;
  const int nt = blockIdx.y;
#pragma unroll
  for (int i = 0; i < 4; ++i) {
    int idx = i * 256 + tid;
    int c_l = idx >> 4, n4 = (idx & 15) * 4;
    float4 v = *reinterpret_cast<const float4*>(&Wp[(size_t)(ct * 64 + c_l) * 1024 + nt * 64 + n4]);
    tle[(n4 + 0) * 72 + c_l] = f2bf(v.x);
    tle[(n4 + 1) * 72 + c_l] = f2bf(v.y);
    tle[(n4 + 2) * 72 + c_l] = f2bf(v.z);
    tle[(n4 + 3) * 72 + c_l] = f2bf(v.w);
  }
  __syncthreads();
#pragma unroll
  for (int i = 0; i < 2; ++i) {
    int idx = i * 256 + tid;
    int n_o = idx >> 3, c8 = (idx & 7) * 8;
    uint4 v = LDU4(&tle[n_o * 72 + c8]);
    *reinterpret_cast<uint4*>(&wpt[(size_t)(nt * 64 + n_o) * 1024 + ct * 64 + c8]) = v;
  }
}

// qkv V-part -> vT[(bb*16+h)*64+d][2048], sigma-permuted per 64-token tile.
__global__ __launch_bounds__(256)
void transpose_v_kernel(const u16* __restrict__ qkv, u16* __restrict__ vT) {
  __shared__ alignas(16) u16 tle[64 * 72];
  const int tid = threadIdx.x;
  const int tt = blockIdx.x;  // token tile 0..31
  const int h = blockIdx.y;   // 0..15
  const int bb = blockIdx.z;  // 0..3
  const size_t rbase = ((size_t)bb * 2048 + tt * 64) * 3072 + 2048 + h * 64;
#pragma unroll
  for (int i = 0; i < 2; ++i) {
    int idx = i * 256 + tid;  // 0..511
    int s = idx >> 3, c8 = (idx & 7) * 8;
    *reinterpret_cast<uint4*>(&tle[s * 72 + c8]) = LDU4(&qkv[rbase + (size_t)s * 3072 + c8]);
  }
  __syncthreads();
#pragma unroll
  for (int i = 0; i < 2; ++i) {
    int idx = i * 256 + tid;
    int d = idx >> 3, cb = idx & 7;
    uint4 o;
    o.x = (uint)tle[(2 * cb + 0) * 72 + d] | ((uint)tle[(16 + 2 * cb + 0) * 72 + d] << 16);
    o.y = (uint)tle[(32 + 2 * cb + 0) * 72 + d] | ((uint)tle[(48 + 2 * cb + 0) * 72 + d] << 16);
    o.z = (uint)tle[(2 * cb + 1) * 72 + d] | ((uint)tle[(16 + 2 * cb + 1) * 72 + d] << 16);
    o.w = (uint)tle[(32 + 2 * cb + 1) * 72 + d] | ((uint)tle[(48 + 2 * cb + 1) * 72 + d] << 16);
    *reinterpret_cast<uint4*>(
        &vT[((size_t)(bb * 16 + h) * 64 + d) * 2048 + tt * 64 + cb * 8]) = o;
  }
}

// ---------------- gemm13: 128x256, BK=32, 48KB LDS (3 blocks/CU) — for QKV ----------------

template <bool OUT_F32>
__global__ __launch_bounds__(512, 4)
void gemm13_kernel(const u16* __restrict__ A, const u16* __restrict__ Bt,
                   const float* __restrict__ bias, void* __restrict__ Cout,
                   int M, int N, int K, int nbn) {
  __shared__ alignas(16) u16 LA[2 * 4096];  // 2 x (128x32) = 16 KB
  __shared__ alignas(16) u16 LB[2 * 8192];  // 2 x (256x32) = 32 KB

  const int tid = threadIdx.x;
  const int lane = tid & 63;
  const int wave = tid >> 6;
  const int wm = wave >> 2;
  const int wn = wave & 3;
  const int fr = lane & 15;
  const int kg = lane >> 4;
  const int r4 = kg * 4;

  const int nwg = gridDim.x;
  const int swz = (blockIdx.x & 7) * (nwg >> 3) + (blockIdx.x >> 3);
  const int m0 = (swz / nbn) * 128;
  const int n0 = (swz % nbn) * 256;
  const int NT = K >> 5;

  const int srow = tid >> 2;  // 0..127
  const int sgcol = (((tid & 3) ^ ((srow >> 1) & 3)) << 3);
  const size_t aOff = (size_t)(m0 + srow) * K + sgcol;
  const size_t bOff = (size_t)(n0 + srow) * K + sgcol;
  const int ldst = tid * 8;

  auto stageA = [&](int kt, u16* d) {
    gload_lds16(A + aOff + (size_t)kt * 32, d + ldst);
  };
  auto stageB = [&](int kt, u16* d) {
    gload_lds16(Bt + bOff + (size_t)kt * 32, d + ldst);
    gload_lds16(Bt + bOff + (size_t)128 * K + (size_t)kt * 32, d + 4096 + ldst);
  };

  f32x4 acc[4][4] = {};

  stageA(0, LA);
  stageB(0, LB);
  asm volatile("s_waitcnt vmcnt(0)" ::: "memory");
  bar();

  for (int kt = 0; kt < NT; ++kt) {
    const bool st1 = (kt + 1 < NT);
    u16* la = LA + (kt & 1) * 4096;
    u16* lb = LB + (kt & 1) * 8192;

    if (st1) {
      stageA(kt + 1, LA + ((kt + 1) & 1) * 4096);
      stageB(kt + 1, LB + ((kt + 1) & 1) * 8192);
    }

    bf16x8 aF[4], bF[4];
#pragma unroll
    for (int m = 0; m < 4; ++m) {
      const int R = wm * 64 + m * 16 + fr;
      aF[m] = LD8(&la[R * 32 + ((kg ^ ((R >> 1) & 3)) << 3)]);
    }
#pragma unroll
    for (int n = 0; n < 4; ++n) {
      const int R = wn * 64 + n * 16 + fr;
      bF[n] = LD8(&lb[R * 32 + ((kg ^ ((R >> 1) & 3)) << 3)]);
    }

    __builtin_amdgcn_s_setprio(1);
#pragma unroll
    for (int m = 0; m < 4; ++m)
#pragma unroll
      for (int n = 0; n < 4; ++n)
        acc[m][n] = mfma16(aF[m], bF[n], acc[m][n]);
    __builtin_amdgcn_s_setprio(0);

    if (st1) {
      asm volatile("s_waitcnt vmcnt(0)" ::: "memory");
      bar();
    }
  }

#pragma unroll
  for (int m = 0; m < 4; ++m) {
    const int row = m0 + wm * 64 + m * 16 + r4;
#pragma unroll
    for (int n = 0; n < 4; ++n) {
      const int col = n0 + wn * 64 + n * 16 + fr;
      const float bv = bias[col];
#pragma unroll
      for (int r = 0; r < 4; ++r) {
        float v = acc[m][n][r] + bv;
        size_t off = (size_t)(row + r) * N + col;
        if constexpr (OUT_F32) reinterpret_cast<float*>(Cout)[off] = v;
        else                   reinterpret_cast<u16*>(Cout)[off] = f2bf(v);
      }
    }
  }
}

// ---------------- gemm9: 128x256, BK=64, A-dbuf + B-tribuf (counted vmcnt) — for proj ----------------

template <bool OUT_F32>
__global__ __launch_bounds__(512, 2)
void gemm9_kernel(const u16* __restrict__ A, const u16* __restrict__ Bt,
                  const float* __restrict__ bias, void* __restrict__ Cout,
                  int M, int N, int K, int nbn) {
  __shared__ alignas(16) u16 LA[2 * 8192];
  __shared__ alignas(16) u16 LB[3 * 16384];

  const int tid = threadIdx.x;
  const int lane = tid & 63;
  const int wave = tid >> 6;
  const int wm = wave >> 2;
  const int wn = wave & 3;
  const int fr = lane & 15;
  const int kg = lane >> 4;
  const int f7 = fr & 7;
  const int r4 = kg * 4;

  const int nwg = gridDim.x;
  const int swz = (blockIdx.x & 7) * (nwg >> 3) + (blockIdx.x >> 3);
  const int m0 = (swz / nbn) * 128;
  const int n0 = (swz % nbn) * 256;
  const int NT = K >> 6;

  const int srow = tid >> 3;
  const int sgcol = ((tid & 7) ^ (srow & 7)) << 3;
  const size_t aOff = (size_t)(m0 + srow) * K + sgcol;
  const size_t bOff = (size_t)(n0 + srow) * K + sgcol;
  const int ldst = tid * 8;

  auto stageA = [&](int kt, u16* labuf) {
    gload_lds16(A + aOff + (size_t)kt * 64, labuf + ldst);
    gload_lds16(A + aOff + (size_t)64 * K + (size_t)kt * 64, labuf + 4096 + ldst);
  };
  auto stageB = [&](int kt, u16* lbbuf) {
    gload_lds16(Bt + bOff + (size_t)kt * 64, lbbuf + ldst);
    gload_lds16(Bt + bOff + (size_t)64 * K + (size_t)kt * 64, lbbuf + 4096 + ldst);
    gload_lds16(Bt + bOff + (size_t)128 * K + (size_t)kt * 64, lbbuf + 8192 + ldst);
    gload_lds16(Bt + bOff + (size_t)192 * K + (size_t)kt * 64, lbbuf + 12288 + ldst);
  };

  f32x4 acc[4][4] = {};

  stageA(0, LA);
  stageB(0, LB);
  if (NT > 1) {
    stageB(1, LB + 16384);
    asm volatile("s_waitcnt vmcnt(4)" ::: "memory");
  } else {
    asm volatile("s_waitcnt vmcnt(0)" ::: "memory");
  }
  bar();

  for (int kt = 0; kt < NT; ++kt) {
    const bool st1 = (kt + 1 < NT);
    const bool st2 = (kt + 2 < NT);
    u16* laCur = LA + (kt & 1) * 8192;
    u16* lbCur = LB + (kt % 3) * 16384;

    if (st1) stageA(kt + 1, LA + ((kt + 1) & 1) * 8192);
    if (st2) stageB(kt + 2, LB + ((kt + 2) % 3) * 16384);

    bf16x8 aF[4][2], bF[4][2];
#pragma unroll
    for (int m = 0; m < 4; ++m)
#pragma unroll
      for (int ks = 0; ks < 2; ++ks)
        aF[m][ks] = LD8(&laCur[wm * 4096 + (m * 16 + fr) * 64 + (((ks * 4 + kg) ^ f7) << 3)]);
#pragma unroll
    for (int n = 0; n < 4; ++n)
#pragma unroll
      for (int ks = 0; ks < 2; ++ks)
        bF[n][ks] = LD8(&lbCur[wn * 4096 + (n * 16 + fr) * 64 + (((ks * 4 + kg) ^ f7) << 3)]);

    __builtin_amdgcn_s_setprio(1);
#pragma unroll
    for (int ks = 0; ks < 2; ++ks)
#pragma unroll
      for (int m = 0; m < 4; ++m)
#pragma unroll
        for (int n = 0; n < 4; ++n)
          acc[m][n] = mfma16(aF[m][ks], bF[n][ks], acc[m][n]);
    __builtin_amdgcn_s_setprio(0);

    if (st1) {
      if (st2) asm volatile("s_waitcnt vmcnt(4)" ::: "memory");
      else     asm volatile("s_waitcnt vmcnt(0)" ::: "memory");
      bar();
    }
  }

#pragma unroll
  for (int m = 0; m < 4; ++m) {
    const int row = m0 + wm * 64 + m * 16 + r4;
#pragma unroll
    for (int n = 0; n < 4; ++n) {
      const int col = n0 + wn * 64 + n * 16 + fr;
      const float bv = bias[col];
#pragma unroll
      for (int r = 0; r < 4; ++r) {
        float v = acc[m][n][r] + bv;
        size_t off = (size_t)(row + r) * N + col;
        if constexpr (OUT_F32) reinterpret_cast<float*>(Cout)[off] = v;
        else                   reinterpret_cast<u16*>(Cout)[off] = f2bf(v);
      }
    }
  }
}

// ---------------- causal flash attention: 2 waves x 32 q-rows (unchanged, r10) ----------------

__global__ __launch_bounds__(128, 2)
void attn_kernel(const u16* __restrict__ qkv, const u16* __restrict__ vT,
                 u16* __restrict__ obuf) {
  __shared__ alignas(16) u16 Ks[64 * 72];
  __shared__ alignas(16) u16 Vs[64 * 72];
  __shared__ alignas(16) u16 Ps[2][32 * 72];

  const int tid = threadIdx.x;
  const int lane = tid & 63;
  const int wave = tid >> 6;  // 0..1

  const int gid = blockIdx.x;
  const int xcd = gid & 7;
  const int jj = gid >> 3;
  const int g = xcd * 8 + (jj >> 4);
  const int pair = jj & 15;
  const int bb = g >> 4;
  const int h = g & 15;

  const size_t baseQ = (size_t)bb * 2048 * 3072 + h * 64;
  const size_t baseK = baseQ + 1024;
  const size_t baseVt = (size_t)(bb * 16 + h) * 64 * 2048;

  const int fr = lane & 15;
  const int kg8 = (lane >> 4) * 8;
  const int qw32 = wave * 32;
  const int r4 = (lane >> 4) * 4;

  const int rrA = tid >> 3;       // 0..15
  const int cA8 = (tid & 7) * 8;
  const size_t gK = (size_t)rrA * 3072 + cA8;
  const size_t gV = (size_t)rrA * 2048 + cA8;
  const int lof = rrA * 72 + cA8;
  u16* __restrict__ Pw = &Ps[wave][0];

  for (int half = 0; half < 2; ++half) {
    const int qt = half ? (31 - pair) : pair;
    const int q0 = qt * 64;
    const int nt = qt + 1;

    const u16* qrow0 = &qkv[baseQ + (size_t)(q0 + qw32 + fr) * 3072 + kg8];
    bf16x8 aq00 = LD8(qrow0), aq01 = LD8(qrow0 + 32);
    const u16* qrow1 = qrow0 + 16 * 3072;
    bf16x8 aq10 = LD8(qrow1), aq11 = LD8(qrow1 + 32);

    float lsA0 = 0.f, lsA1 = 0.f, lsA2 = 0.f, lsA3 = 0.f;
    float lsB0 = 0.f, lsB1 = 0.f, lsB2 = 0.f, lsB3 = 0.f;
    f32x4 oA0 = {}, oA1 = {}, oA2 = {}, oA3 = {};
    f32x4 oB0 = {}, oB1 = {}, oB2 = {}, oB3 = {};

    uint4 kr0 = LDU4(&qkv[baseK + gK]);
    uint4 kr1 = LDU4(&qkv[baseK + gK + 49152]);
    uint4 kr2 = LDU4(&qkv[baseK + gK + 98304]);
    uint4 kr3 = LDU4(&qkv[baseK + gK + 147456]);
    uint4 vr0 = LDU4(&vT[baseVt + gV]);
    uint4 vr1 = LDU4(&vT[baseVt + gV + 32768]);
    uint4 vr2 = LDU4(&vT[baseVt + gV + 65536]);
    uint4 vr3 = LDU4(&vT[baseVt + gV + 98304]);

    for (int t = 0; t < nt; ++t) {
      __syncthreads();
      *reinterpret_cast<uint4*>(&Ks[lof]) = kr0;
      *reinterpret_cast<uint4*>(&Ks[lof + 1152]) = kr1;
      *reinterpret_cast<uint4*>(&Ks[lof + 2304]) = kr2;
      *reinterpret_cast<uint4*>(&Ks[lof + 3456]) = kr3;
      *reinterpret_cast<uint4*>(&Vs[lof]) = vr0;
      *reinterpret_cast<uint4*>(&Vs[lof + 1152]) = vr1;
      *reinterpret_cast<uint4*>(&Vs[lof + 2304]) = vr2;
      *reinterpret_cast<uint4*>(&Vs[lof + 3456]) = vr3;
      if (t + 1 < nt) {
        const u16* nk = &qkv[baseK + (size_t)(t + 1) * 196608];
        const u16* nv = &vT[baseVt + (size_t)(t + 1) * 64];
        kr0 = LDU4(nk + gK);
        kr1 = LDU4(nk + gK + 49152);
        kr2 = LDU4(nk + gK + 98304);
        kr3 = LDU4(nk + gK + 147456);
        vr0 = LDU4(nv + gV);
        vr1 = LDU4(nv + gV + 32768);
        vr2 = LDU4(nv + gV + 65536);
        vr3 = LDU4(nv + gV + 98304);
      }
      __syncthreads();

      f32x4 sA0 = {}, sA1 = {}, sA2 = {}, sA3 = {};
      f32x4 sB0 = {}, sB1 = {}, sB2 = {}, sB3 = {};
      {
        bf16x8 b;
        __builtin_amdgcn_s_setprio(1);
        b = LD8(&Ks[(fr) * 72 + kg8]);           sA0 = mfma16(aq00, b, sA0); sB0 = mfma16(aq10, b, sB0);
        b = LD8(&Ks[(16 + fr) * 72 + kg8]);      sA1 = mfma16(aq00, b, sA1); sB1 = mfma16(aq10, b, sB1);
        b = LD8(&Ks[(32 + fr) * 72 + kg8]);      sA2 = mfma16(aq00, b, sA2); sB2 = mfma16(aq10, b, sB2);
        b = LD8(&Ks[(48 + fr) * 72 + kg8]);      sA3 = mfma16(aq00, b, sA3); sB3 = mfma16(aq10, b, sB3);
        b = LD8(&Ks[(fr) * 72 + 32 + kg8]);      sA0 = mfma16(aq01, b, sA0); sB0 = mfma16(aq11, b, sB0);
        b = LD8(&Ks[(16 + fr) * 72 + 32 + kg8]); sA1 = mfma16(aq01, b, sA1); sB1 = mfma16(aq11, b, sB1);
        b = LD8(&Ks[(32 + fr) * 72 + 32 + kg8]); sA2 = mfma16(aq01, b, sA2); sB2 = mfma16(aq11, b, sB2);
        b = LD8(&Ks[(48 + fr) * 72 + 32 + kg8]); sA3 = mfma16(aq01, b, sA3); sB3 = mfma16(aq11, b, sB3);
        __builtin_amdgcn_s_setprio(0);
      }

      const bool diag = (t == nt - 1);
#define SM_ROW_G(S0, S1, S2, S3, LS, RB, r)                                    \
      {                                                                        \
        const int qg = qw32 + RB + r4 + r;                                     \
        float p0 = fexp2(S0[r]);                                               \
        float p1 = fexp2(S1[r]);                                               \
        float p2 = fexp2(S2[r]);                                               \
        float p3 = fexp2(S3[r]);                                               \
        if (diag) {                                                            \
          if (fr > qg) p0 = 0.f;                                               \
          if (fr + 16 > qg) p1 = 0.f;                                          \
          if (fr + 32 > qg) p2 = 0.f;                                          \
          if (fr + 48 > qg) p3 = 0.f;                                          \
        }                                                                      \
        LS += (p0 + p1) + (p2 + p3);                                           \
        uint2 w;                                                               \
        w.x = pack2(p0, p1);                                                   \
        w.y = pack2(p2, p3);                                                   \
        *reinterpret_cast<uint2*>(&Pw[(RB + r4 + r) * 72 + fr * 4]) = w;       \
      }
      SM_ROW_G(sA0, sA1, sA2, sA3, lsA0, 0, 0)
      SM_ROW_G(sA0, sA1, sA2, sA3, lsA1, 0, 1)
      SM_ROW_G(sA0, sA1, sA2, sA3, lsA2, 0, 2)
      SM_ROW_G(sA0, sA1, sA2, sA3, lsA3, 0, 3)
      SM_ROW_G(sB0, sB1, sB2, sB3, lsB0, 16, 0)
      SM_ROW_G(sB0, sB1, sB2, sB3, lsB1, 16, 1)
      SM_ROW_G(sB0, sB1, sB2, sB3, lsB2, 16, 2)
      SM_ROW_G(sB0, sB1, sB2, sB3, lsB3, 16, 3)
#undef SM_ROW_G

      {
        bf16x8 pfA = LD8(&Pw[fr * 72 + kg8]);
        bf16x8 pfB = LD8(&Pw[(16 + fr) * 72 + kg8]);
        bf16x8 v;
        __builtin_amdgcn_s_setprio(1);
        v = LD8(&Vs[(fr) * 72 + kg8]);           oA0 = mfma16(pfA, v, oA0); oB0 = mfma16(pfB, v, oB0);
        v = LD8(&Vs[(16 + fr) * 72 + kg8]);      oA1 = mfma16(pfA, v, oA1); oB1 = mfma16(pfB, v, oB1);
        v = LD8(&Vs[(32 + fr) * 72 + kg8]);      oA2 = mfma16(pfA, v, oA2); oB2 = mfma16(pfB, v, oB2);
        v = LD8(&Vs[(48 + fr) * 72 + kg8]);      oA3 = mfma16(pfA, v, oA3); oB3 = mfma16(pfB, v, oB3);
        pfA = LD8(&Pw[fr * 72 + 32 + kg8]);
        pfB = LD8(&Pw[(16 + fr) * 72 + 32 + kg8]);
        v = LD8(&Vs[(fr) * 72 + 32 + kg8]);      oA0 = mfma16(pfA, v, oA0); oB0 = mfma16(pfB, v, oB0);
        v = LD8(&Vs[(16 + fr) * 72 + 32 + kg8]); oA1 = mfma16(pfA, v, oA1); oB1 = mfma16(pfB, v, oB1);
        v = LD8(&Vs[(32 + fr) * 72 + 32 + kg8]); oA2 = mfma16(pfA, v, oA2); oB2 = mfma16(pfB, v, oB2);
        v = LD8(&Vs[(48 + fr) * 72 + 32 + kg8]); oA3 = mfma16(pfA, v, oA3); oB3 = mfma16(pfB, v, oB3);
        __builtin_amdgcn_s_setprio(0);
      }
    }

#define EPI_G(O0, O1, O2, O3, LS, RB, r)                                       \
    {                                                                          \
      float s = LS;                                                            \
      s += __shfl_xor(s, 1);                                                   \
      s += __shfl_xor(s, 2);                                                   \
      s += __shfl_xor(s, 4);                                                   \
      s += __shfl_xor(s, 8);                                                   \
      const float inv = 1.0f / s;                                              \
      const int qg = q0 + qw32 + RB + r4 + r;                                  \
      const size_t rowoff = ((size_t)bb * 2048 + qg) * 1024 + h * 64;          \
      obuf[rowoff + fr] = f2bf(O0[r] * inv);                                   \
      obuf[rowoff + 16 + fr] = f2bf(O1[r] * inv);                              \
      obuf[rowoff + 32 + fr] = f2bf(O2[r] * inv);                              \
      obuf[rowoff + 48 + fr] = f2bf(O3[r] * inv);                              \
    }
    EPI_G(oA0, oA1, oA2, oA3, lsA0, 0, 0)
    EPI_G(oA0, oA1, oA2, oA3, lsA1, 0, 1)
    EPI_G(oA0, oA1, oA2, oA3, lsA2, 0, 2)
    EPI_G(oA0, oA1, oA2, oA3, lsA3, 0, 3)
    EPI_G(oB0, oB1, oB2, oB3, lsB0, 16, 0)
    EPI_G(oB0, oB1, oB2, oB3, lsB1, 16, 1)
    EPI_G(oB0, oB1, oB2, oB3, lsB2, 16, 2)
    EPI_G(oB0, oB1, oB2, oB3, lsB3, 16, 3)
#undef EPI_G
  }
}

// ---------------- launch ----------------

extern "C" void kernel_launch(void* const* d_in, const int* in_sizes, int n_in,
                              void* d_out, int out_size, void* d_ws, size_t ws_size,
                              hipStream_t stream) {
  const float* x  = (const float*)d_in[0];
  const float* Wq = (const float*)d_in[1];
  const float* bq = (const float*)d_in[2];
  const float* Wk = (const float*)d_in[3];
  const float* bk = (const float*)d_in[4];
  const float* Wv = (const float*)d_in[5];
  const float* bv = (const float*)d_in[6];
  const float* Wp = (const float*)d_in[7];
  const float* bp = (const float*)d_in[8];

  char* ws = (char*)d_ws;
  size_t off = 0;
  auto alloc = [&](size_t bytes) -> void* {
    void* p = ws + off;
    off += (bytes + 255) & ~(size_t)255;
    return p;
  };
  u16*   xb     = (u16*)  alloc((size_t)8192 * 1024 * 2);  // reused as vT after QKV GEMM
  u16*   wqkv_t = (u16*)  alloc((size_t)3072 * 1024 * 2);
  float* biasq  = (float*)alloc((size_t)3072 * 4);
  u16*   wpt    = (u16*)  alloc((size_t)1024 * 1024 * 2);
  u16*   qkv    = (u16*)  alloc((size_t)8192 * 3072 * 2);
  u16*   obuf   = (u16*)  alloc((size_t)8192 * 1024 * 2);
  u16*   vT     = xb;  // xb is dead after the QKV GEMM; vT is exactly 16 MB too
  (void)ws_size; (void)in_sizes; (void)n_in; (void)out_size;

  cvt_x_kernel<<<2048, 256, 0, stream>>>(x, xb, 8192 * 1024 / 8);
  cvt_wqkv_kernel<<<dim3(16, 16, 3), 256, 0, stream>>>(Wq, Wk, Wv, bq, bk, bv, wqkv_t, biasq);
  cvt_wp_kernel<<<dim3(16, 16), 256, 0, stream>>>(Wp, wpt);
  gemm13_kernel<false><<<768, 512, 0, stream>>>(xb, wqkv_t, biasq, qkv, 8192, 3072, 1024, 12);
  transpose_v_kernel<<<dim3(32, 16, 4), 256, 0, stream>>>(qkv, vT);
  attn_kernel<<<1024, 128, 0, stream>>>(qkv, vT, obuf);
  gemm9_kernel<true><<<256, 512, 0, stream>>>(obuf, wpt, bp, d_out, 8192, 1024, 1024, 4);
}